// Round 9
// baseline (363.953 us; speedup 1.0000x reference)
//
#include <hip/hip_runtime.h>
#include <math.h>

// Problem constants (B=32, T=128, K=16, L=16); N = 4096 tokens, 784 pixels, hidden 400.
// Precision strategy: all GEMMs single-term fp16 MFMA with fp32 accumulate.
// Pipeline:
//   k_prep  : decw -> fp16 [896][448]; enc w1 -> fp16 [512][800]; y -> fp16
//             yh[4096][800] (aliased onto hkh region); zero lb
//   k_enc1  : h = relu(y @ W1^T + b1), A staged from yh fp16
//   k_enc2z : z[4096,16]
//   k_basehk: base[16n][448] in LDS -> hkh[16][4096][448] fp16 (fused)
//   k_dec6  : k_dec2 champion (147us) with B moved LDS->per-lane registers
//             (dwh is L2-resident; fragment addr directly computable) and the
//             freed 16KB LDS used to double-buffer A (the L3-resident 58.7MB
//             operand): gll A(hc+1) issued BEFORE MFMA(hc), single
//             __syncthreads per phase (was 2). Residency held at 4 blk/CU
//             (LDS 33KB unchanged) - R5/R6/R7 confounds removed.
//             k_dec occupancy ladder: 4blk=145 / 3blk=165 / 2blk=198 us.
//   k_hmm   : fwd/bwd + gamma + xi fused
//   fallback path (small ws): k_enc1f (f32 y) + k_base + k_dec1.

typedef _Float16 h8v __attribute__((ext_vector_type(8)));   // MFMA A/B frag (4 VGPRs)
typedef _Float16 h4v __attribute__((ext_vector_type(4)));
typedef float f16v __attribute__((ext_vector_type(16)));    // MFMA C/D frag

__device__ __forceinline__ void gll16(const void* g, void* l) {
  __builtin_amdgcn_global_load_lds(
      (const __attribute__((address_space(1))) void*)g,
      (__attribute__((address_space(3))) void*)l, 16, 0, 0);
}

// ---------------- k_prep ----------------
__global__ __launch_bounds__(256)
void k_prep(const float* __restrict__ dw, const float* __restrict__ ew1,
            const float* __restrict__ y, _Float16* __restrict__ dwh,
            _Float16* __restrict__ w1h, _Float16* __restrict__ yh,
            float* __restrict__ lb) {
  int idx = blockIdx.x * 256 + threadIdx.x;
  if (idx < 65536) lb[idx] = 0.f;   // zero BCE accumulator (k_dec atomicAdds into it)
  if (idx < 896 * 448) {
    int o = idx / 448, h2 = idx - o * 448;
    float v = (o < 784 && h2 < 400) ? dw[o * 400 + h2] : 0.f;
    dwh[idx] = (_Float16)v;
  } else if (idx < 811008) {
    int j = idx - 896 * 448;
    int i = j / 800, kc = j - i * 800;
    float v = (i < 400 && kc < 784) ? ew1[i * 784 + kc] : 0.f;
    w1h[j] = (_Float16)v;
  } else if (idx < 4087808) {
    int j = idx - 811008;
    int n = j / 800, c = j - n * 800;
    float v = (c < 784) ? y[n * 784 + c] : 0.f;
    yh[j] = (_Float16)v;
  }
}

// ---------------- K1: h = relu(y @ W1^T + b1) via fp16 MFMA (yh fp16 A) ------
#define E1ST 40
__global__ __launch_bounds__(256, 2)
void k_enc1(const _Float16* __restrict__ yh, const _Float16* __restrict__ w1h,
            const float* __restrict__ b1, float* __restrict__ hout) {
  __shared__ __align__(16) _Float16 Ah[64 * E1ST];
  __shared__ __align__(16) _Float16 Bh[128 * E1ST];
  const int tid = threadIdx.x;
  const int i0 = blockIdx.x * 128;
  const int n0 = blockIdx.y * 64;
  const int wav = tid >> 6, lane = tid & 63;
  const int wn = wav >> 1, wi = wav & 1;
  const int ln = lane & 31, kg = lane >> 5;

  f16v acc[2];
#pragma unroll
  for (int j = 0; j < 2; ++j)
#pragma unroll
    for (int r = 0; r < 16; ++r) acc[j][r] = 0.f;

  const int ar = tid >> 2, ac8 = (tid & 3) * 8;   // A: 64 rows x 4 x8, 1/thread
  const int br = tid >> 2, bg = (tid & 3) * 8;    // B: 128 rows x 4 x8, 2/thread

#pragma unroll 1
  for (int hc = 0; hc < 25; ++hc) {
    const int h0 = hc * 32;
    __syncthreads();
    *(h8v*)&Ah[ar * E1ST + ac8] = *(const h8v*)&yh[(n0 + ar) * 800 + h0 + ac8];
#pragma unroll
    for (int it = 0; it < 2; ++it) {
      int r = br + 64 * it;
      *(h8v*)&Bh[r * E1ST + bg] = *(const h8v*)&w1h[(i0 + r) * 800 + h0 + bg];
    }
    __syncthreads();
#pragma unroll
    for (int kk = 0; kk < 2; ++kk) {
      const int ko = kk * 16 + kg * 8;
      h8v a  = *(const h8v*)&Ah[(wn * 32 + ln) * E1ST + ko];
      h8v b0 = *(const h8v*)&Bh[(wi * 64 + ln) * E1ST + ko];
      h8v b1 = *(const h8v*)&Bh[(wi * 64 + 32 + ln) * E1ST + ko];
      acc[0] = __builtin_amdgcn_mfma_f32_32x32x16_f16(a, b0, acc[0], 0, 0, 0);
      acc[1] = __builtin_amdgcn_mfma_f32_32x32x16_f16(a, b1, acc[1], 0, 0, 0);
    }
  }
#pragma unroll
  for (int j = 0; j < 2; ++j) {
    const int i = i0 + wi * 64 + j * 32 + ln;
    if (i < 400) {
      const float bias = b1[i];
#pragma unroll
      for (int reg = 0; reg < 16; ++reg) {
        const int row = n0 + wn * 32 + (reg & 3) + 8 * (reg >> 2) + 4 * kg;
        hout[row * 400 + i] = fmaxf(acc[j][reg] + bias, 0.f);
      }
    }
  }
}

// ---------------- K1 fallback: f32 y input (small-ws path) -------------------
__global__ __launch_bounds__(256, 2)
void k_enc1f(const float* __restrict__ y, const _Float16* __restrict__ w1h,
             const float* __restrict__ b1, float* __restrict__ hout) {
  __shared__ __align__(16) _Float16 Ah[64 * E1ST];
  __shared__ __align__(16) _Float16 Bh[128 * E1ST];
  const int tid = threadIdx.x;
  const int i0 = blockIdx.x * 128;
  const int n0 = blockIdx.y * 64;
  const int wav = tid >> 6, lane = tid & 63;
  const int wn = wav >> 1, wi = wav & 1;
  const int ln = lane & 31, kg = lane >> 5;

  f16v acc[2];
#pragma unroll
  for (int j = 0; j < 2; ++j)
#pragma unroll
    for (int r = 0; r < 16; ++r) acc[j][r] = 0.f;

  const int ar = tid >> 3, ac4 = (tid & 7) * 4;
  const int br = tid >> 2, bg = (tid & 3) * 8;

#pragma unroll 1
  for (int hc = 0; hc < 25; ++hc) {
    const int h0 = hc * 32;
    __syncthreads();
#pragma unroll
    for (int it = 0; it < 2; ++it) {
      int r = ar + 32 * it;
      float4 a = make_float4(0.f, 0.f, 0.f, 0.f);
      if (h0 + ac4 < 784) a = *(const float4*)&y[(n0 + r) * 784 + h0 + ac4];
      h4v hv;
      hv[0] = (_Float16)a.x; hv[1] = (_Float16)a.y;
      hv[2] = (_Float16)a.z; hv[3] = (_Float16)a.w;
      *(h4v*)&Ah[r * E1ST + ac4] = hv;
    }
#pragma unroll
    for (int it = 0; it < 2; ++it) {
      int r = br + 64 * it;
      *(h8v*)&Bh[r * E1ST + bg] = *(const h8v*)&w1h[(i0 + r) * 800 + h0 + bg];
    }
    __syncthreads();
#pragma unroll
    for (int kk = 0; kk < 2; ++kk) {
      const int ko = kk * 16 + kg * 8;
      h8v a  = *(const h8v*)&Ah[(wn * 32 + ln) * E1ST + ko];
      h8v b0 = *(const h8v*)&Bh[(wi * 64 + ln) * E1ST + ko];
      h8v b1 = *(const h8v*)&Bh[(wi * 64 + 32 + ln) * E1ST + ko];
      acc[0] = __builtin_amdgcn_mfma_f32_32x32x16_f16(a, b0, acc[0], 0, 0, 0);
      acc[1] = __builtin_amdgcn_mfma_f32_32x32x16_f16(a, b1, acc[1], 0, 0, 0);
    }
  }
#pragma unroll
  for (int j = 0; j < 2; ++j) {
    const int i = i0 + wi * 64 + j * 32 + ln;
    if (i < 400) {
      const float bias = b1[i];
#pragma unroll
      for (int reg = 0; reg < 16; ++reg) {
        const int row = n0 + wn * 32 + (reg & 3) + 8 * (reg >> 2) + 4 * kg;
        hout[row * 400 + i] = fmaxf(acc[j][reg] + bias, 0.f);
      }
    }
  }
}

// ---------------- K2: ml = h @ W2^T + b2, z = mu + eps*exp(0.5*logvar) --------
__global__ __launch_bounds__(128, 2)
void k_enc2z(const float* __restrict__ h, const float* __restrict__ w2,
             const float* __restrict__ b2, const float* __restrict__ eps,
             float* __restrict__ z) {
  __shared__ __align__(16) float h_lds[16 * 400];
  __shared__ __align__(16) float w2_lds[32 * 404];
  __shared__ float ml_lds[16 * 32];
  const int tid = threadIdx.x;
  const int n0 = blockIdx.x * 16;
  for (int idx = tid; idx < 1600; idx += 128) {
    int r = idx / 100, c = idx - r * 100;
    *(float4*)&h_lds[r * 400 + c * 4] = *(const float4*)&h[(n0 + r) * 400 + c * 4];
  }
  for (int idx = tid; idx < 3200; idx += 128) {
    int r = idx / 100, c = idx - r * 100;
    *(float4*)&w2_lds[r * 404 + c * 4] = *(const float4*)&w2[r * 400 + c * 4];
  }
  __syncthreads();
  const int c_ = tid & 31, n4 = tid >> 5;
  float a0 = 0.f, a1 = 0.f, a2 = 0.f, a3 = 0.f;
  for (int q = 0; q < 100; ++q) {
    float4 wv = *(const float4*)&w2_lds[c_ * 404 + q * 4];
    float4 h0 = *(const float4*)&h_lds[(n4 * 4 + 0) * 400 + q * 4];
    float4 h1 = *(const float4*)&h_lds[(n4 * 4 + 1) * 400 + q * 4];
    float4 h2 = *(const float4*)&h_lds[(n4 * 4 + 2) * 400 + q * 4];
    float4 h3 = *(const float4*)&h_lds[(n4 * 4 + 3) * 400 + q * 4];
    a0 += h0.x * wv.x + h0.y * wv.y + h0.z * wv.z + h0.w * wv.w;
    a1 += h1.x * wv.x + h1.y * wv.y + h1.z * wv.z + h1.w * wv.w;
    a2 += h2.x * wv.x + h2.y * wv.y + h2.z * wv.z + h2.w * wv.w;
    a3 += h3.x * wv.x + h3.y * wv.y + h3.z * wv.z + h3.w * wv.w;
  }
  const float bb = b2[c_];
  ml_lds[(n4 * 4 + 0) * 32 + c_] = a0 + bb;
  ml_lds[(n4 * 4 + 1) * 32 + c_] = a1 + bb;
  ml_lds[(n4 * 4 + 2) * 32 + c_] = a2 + bb;
  ml_lds[(n4 * 4 + 3) * 32 + c_] = a3 + bb;
  __syncthreads();
  for (int t = tid; t < 256; t += 128) {
    int n2 = t >> 4, l = t & 15;
    float mu = ml_lds[n2 * 32 + l];
    float lv = ml_lds[n2 * 32 + 16 + l];
    z[(n0 + n2) * 16 + l] = mu + eps[(n0 + n2) * 16 + l] * expf(0.5f * lv);
  }
}

// ---------------- k_basehk: fused base + hk (big-ws path) --------------------
__global__ __launch_bounds__(256, 2)
void k_basehk(const float* __restrict__ z, const float* __restrict__ dfw,
              const float* __restrict__ dfb, _Float16* __restrict__ hkh) {
  __shared__ float z_lds[16 * 16];
  __shared__ __align__(16) float wz[400 * 20];   // phase1: Wz rows; phase2: wxT[16][448]
  __shared__ __align__(16) float base[16 * 448];
  const int tid = threadIdx.x;
  const int n0 = blockIdx.x * 16;
  if (tid < 64) {
    int n = tid >> 2, c = (tid & 3) * 4;
    *(float4*)&z_lds[n * 16 + c] = *(const float4*)&z[(n0 + n) * 16 + c];
  }
  for (int idx = tid; idx < 1600; idx += 256) {
    int i = idx >> 2, c = (idx & 3) * 4;
    *(float4*)&wz[i * 20 + c] = *(const float4*)&dfw[i * 32 + c];
  }
  __syncthreads();
  for (int idx = tid; idx < 7168; idx += 256) {
    int n = idx / 448, i = idx - n * 448;
    float acc = 0.f;
    if (i < 400) {
      acc = dfb[i];
#pragma unroll
      for (int q = 0; q < 4; ++q) {
        float4 zv = *(const float4*)&z_lds[n * 16 + q * 4];
        float4 wv = *(const float4*)&wz[i * 20 + q * 4];
        acc += zv.x * wv.x + zv.y * wv.y + zv.z * wv.z + zv.w * wv.w;
      }
    }
    base[n * 448 + i] = acc;
  }
  __syncthreads();
  for (int idx = tid; idx < 7168; idx += 256) {
    int k = idx / 448, hh = idx - k * 448;
    wz[idx] = (hh < 400) ? dfw[hh * 32 + 16 + k] : 0.f;
  }
  __syncthreads();
  for (int s = tid; s < 14336; s += 256) {
    int k = s / 896, r2 = s - k * 896;
    int r = r2 / 56, c8 = r2 - r * 56;
    const float* bp = &base[r * 448 + c8 * 8];
    const float* wp = &wz[k * 448 + c8 * 8];
    float4 b0 = *(const float4*)bp, b1 = *(const float4*)(bp + 4);
    float4 w0 = *(const float4*)wp, w1 = *(const float4*)(wp + 4);
    h8v o;
    o[0] = (_Float16)fmaxf(b0.x + w0.x, 0.f);
    o[1] = (_Float16)fmaxf(b0.y + w0.y, 0.f);
    o[2] = (_Float16)fmaxf(b0.z + w0.z, 0.f);
    o[3] = (_Float16)fmaxf(b0.w + w0.w, 0.f);
    o[4] = (_Float16)fmaxf(b1.x + w1.x, 0.f);
    o[5] = (_Float16)fmaxf(b1.y + w1.y, 0.f);
    o[6] = (_Float16)fmaxf(b1.z + w1.z, 0.f);
    o[7] = (_Float16)fmaxf(b1.w + w1.w, 0.f);
    *(h8v*)&hkh[((size_t)k * 4096 + n0 + r) * 448 + c8 * 8] = o;
  }
}

// ---------------- K3 (fallback path): base_p = z @ Wz^T + dec_fc_b -----------
__global__ __launch_bounds__(256, 4)
void k_base(const float* __restrict__ z, const float* __restrict__ dfw,
            const float* __restrict__ dfb, float* __restrict__ basep) {
  __shared__ float z_lds[16 * 16];
  __shared__ __align__(16) float wz_lds[400 * 20];
  const int tid = threadIdx.x;
  const int n0 = blockIdx.x * 16;
  if (tid < 64) {
    int n = tid >> 2, c = (tid & 3) * 4;
    *(float4*)&z_lds[n * 16 + c] = *(const float4*)&z[(n0 + n) * 16 + c];
  }
  for (int idx = tid; idx < 1600; idx += 256) {
    int i = idx >> 2, c = (idx & 3) * 4;
    *(float4*)&wz_lds[i * 20 + c] = *(const float4*)&dfw[i * 32 + c];
  }
  __syncthreads();
  for (int idx = tid; idx < 7168; idx += 256) {
    int n = idx / 448, i = idx - n * 448;
    float acc = 0.f;
    if (i < 400) {
      acc = dfb[i];
#pragma unroll
      for (int q = 0; q < 4; ++q) {
        float4 zv = *(const float4*)&z_lds[n * 16 + q * 4];
        float4 wv = *(const float4*)&wz_lds[i * 20 + q * 4];
        acc += zv.x * wv.x + zv.y * wv.y + zv.z * wv.z + zv.w * wv.w;
      }
    }
    basep[(n0 + n) * 448 + i] = acc;
  }
}

// ---------------- K4 v6: A dbuf-LDS + B per-lane regs, 1 barrier/phase -------
__global__ __launch_bounds__(256, 2)
void k_dec6(const _Float16* __restrict__ hkh, const _Float16* __restrict__ dwh,
            const float* __restrict__ decb, const float* __restrict__ y,
            float* __restrict__ lb) {
  __shared__ __align__(16) _Float16 Ah[2][128 * 64];   // 2 x 16KB (A dbuf)
  __shared__ float red[256];

  const int tid = threadIdx.x;
  const int id  = blockIdx.x;
  const int lin = (id & 7) * 448 + (id >> 3);   // 3584 = 8 XCD x 448, bijective
  const int n_i = lin / 112;
  const int rem = lin - n_i * 112;
  const int k   = rem / 7;
  const int ot  = rem - k * 7;
  const int n0  = n_i * 128;
  const int o0  = ot * 128;

  const int wav = tid >> 6, lane = tid & 63;
  const int wn = wav >> 1, wo = wav & 1;
  const int ln = lane & 31, kg = lane >> 5;

  // A gll staging (pre-swizzled source, rule #21; champion-verified).
  const int l8 = lane >> 3, l7 = lane & 7;
  const int swh = (l7 * 8) ^ (l8 * 8);
  const _Float16* hkk = hkh + (size_t)k * (4096 * 448);
  const _Float16* pA[4];
#pragma unroll
  for (int i = 0; i < 4; ++i) {
    const int row = wav * 32 + i * 8 + l8;
    pA[i] = hkk + (size_t)(n0 + row) * 448 + swh;
  }

  // B per-lane direct fragments (dwh L2-resident, no barrier needed):
  // fragment addr = row(o)*448 + hc*64 + kk*16 + kg*8; rows < 896 (padded).
  const _Float16* bp0 = dwh + (size_t)(o0 + wo * 64 + ln) * 448 + kg * 8;
  const _Float16* bp1 = bp0 + (size_t)32 * 448;

  f16v acc[2][2];
#pragma unroll
  for (int i = 0; i < 2; ++i)
#pragma unroll
    for (int j = 0; j < 2; ++j)
#pragma unroll
      for (int r = 0; r < 16; ++r) acc[i][j][r] = 0.f;

  // prologue: stage A(0) into buf0.
#pragma unroll
  for (int i = 0; i < 4; ++i) { gll16(pA[i], &Ah[0][(wav * 4 + i) * 512]); pA[i] += 64; }
  __syncthreads();

  const int e0 = (kg * 8) ^ ((ln & 7) * 8);   // read-side swizzle
  const int arow = (wn * 64 + ln) * 64;

#pragma unroll
  for (int hc = 0; hc < 7; ++hc) {
    const int cur = hc & 1;
    const int hoff = hc * 64;
    // B(hc) loads: issued right after barrier; MFMA's first B use waits on them
    // (compiler vmcnt); ~200cyc L2 latency covered by 16 waves/CU TLP.
    h8v b0r[4], b1r[4];
#pragma unroll
    for (int kk = 0; kk < 4; ++kk) {
      b0r[kk] = *(const h8v*)&bp0[hoff + kk * 16];
      b1r[kk] = *(const h8v*)&bp1[hoff + kk * 16];
    }
    // A(hc+1) gll issued BEFORE the MFMA cluster -> full phase to land.
    if (hc < 6) {
#pragma unroll
      for (int i = 0; i < 4; ++i) { gll16(pA[i], &Ah[cur ^ 1][(wav * 4 + i) * 512]); pA[i] += 64; }
    }
    const _Float16* Ac = Ah[cur];
#pragma unroll
    for (int kk = 0; kk < 4; ++kk) {
      const int cx = (kk * 16) ^ e0;
      h8v a0 = *(const h8v*)&Ac[arow + cx];
      h8v a1 = *(const h8v*)&Ac[arow + 2048 + cx];
      acc[0][0] = __builtin_amdgcn_mfma_f32_32x32x16_f16(a0, b0r[kk], acc[0][0], 0, 0, 0);
      acc[1][0] = __builtin_amdgcn_mfma_f32_32x32x16_f16(a1, b0r[kk], acc[1][0], 0, 0, 0);
      acc[0][1] = __builtin_amdgcn_mfma_f32_32x32x16_f16(a0, b1r[kk], acc[0][1], 0, 0, 0);
      acc[1][1] = __builtin_amdgcn_mfma_f32_32x32x16_f16(a1, b1r[kk], acc[1][1], 0, 0, 0);
    }
    if (hc < 6) __syncthreads();   // drains A(hc+1) glls; one barrier per phase
  }

  // epilogue: fused BCE (champion-verified). C/D: col(o)=ln, row=(reg&3)+8*(reg>>2)+4*kg.
  // clip-at-100 provably dead (|x|<=~10): v += softplus(x) - y*x.
  const int obase = o0 + wo * 64;
  const float bj0 = (obase + ln < 784) ? decb[obase + ln] : 0.f;
  const float bj1 = (obase + 32 + ln < 784) ? decb[obase + 32 + ln] : 0.f;
#pragma unroll
  for (int i = 0; i < 2; ++i) {
#pragma unroll
    for (int reg = 0; reg < 16; ++reg) {
      const int row = wn * 64 + i * 32 + (reg & 3) + 8 * (reg >> 2) + 4 * kg;
      float v = 0.f;
#pragma unroll
      for (int j = 0; j < 2; ++j) {
        const int o = obase + j * 32 + ln;
        if (o < 784) {
          float x = acc[i][j][reg] + (j ? bj1 : bj0);
          float yv = y[(n0 + row) * 784 + o];
          float spx = fmaxf(x, 0.f) + __logf(1.f + __expf(-fabsf(x)));
          v += spx - yv * x;
        }
      }
      v += __shfl_xor(v, 1, 64);
      v += __shfl_xor(v, 2, 64);
      v += __shfl_xor(v, 4, 64);
      v += __shfl_xor(v, 8, 64);
      v += __shfl_xor(v, 16, 64);
      if (ln == 0) red[wo * 128 + row] = v;
    }
  }
  __syncthreads();
  if (tid < 128) {
    float s = red[tid] + red[128 + tid];
    atomicAdd(&lb[(n0 + tid) * 16 + k], s);
  }
}

// ---------------- K4 v1 (fallback if ws too small for hkh) -------------------
#define DST 72
__global__ __launch_bounds__(256, 2)
void k_dec1(const float* __restrict__ basep, const float* __restrict__ dfw,
            const _Float16* __restrict__ dwh, const float* __restrict__ decb,
            const float* __restrict__ y, float* __restrict__ lb) {
  __shared__ __align__(16) _Float16 Ah[128 * DST];
  __shared__ __align__(16) _Float16 Bh[128 * DST];
  __shared__ float wx[448];
  __shared__ float red[256];

  const int tid = threadIdx.x;
  const int id  = blockIdx.x;
  const int lin = (id & 7) * 448 + (id >> 3);
  const int n_i = lin / 112;
  const int rem = lin - n_i * 112;
  const int k   = rem / 7;
  const int ot  = rem - k * 7;
  const int n0  = n_i * 128;
  const int o0  = ot * 128;
  const bool full = (ot < 6);

  const int wav = tid >> 6, lane = tid & 63;
  const int wn = wav >> 1, wo = wav & 1;
  const int ln = lane & 31, kg = lane >> 5;

  for (int i = tid; i < 448; i += 256) wx[i] = (i < 400) ? dfw[i * 32 + 16 + k] : 0.f;

  const int ar = tid >> 4, ac4 = (tid & 15) * 4;
  const int br = tid >> 3, bg = (tid & 7) * 8;
  const float* aptr = basep + (long)(n0 + ar) * 448 + ac4;

  float4 apf[8];
#pragma unroll
  for (int it = 0; it < 8; ++it) apf[it] = *(const float4*)&aptr[(16 * it) * 448];

  f16v acc[2][2];
#pragma unroll
  for (int i = 0; i < 2; ++i)
#pragma unroll
    for (int j = 0; j < 2; ++j)
#pragma unroll
      for (int r = 0; r < 16; ++r) acc[i][j][r] = 0.f;

#pragma unroll 1
  for (int hc = 0; hc < 7; ++hc) {
    const int h0 = hc * 64;
    h8v bpf[4];
#pragma unroll
    for (int it = 0; it < 4; ++it)
      bpf[it] = *(const h8v*)&dwh[(o0 + br + 32 * it) * 448 + h0 + bg];
    __syncthreads();
    {
      float4 w = *(const float4*)&wx[h0 + ac4];
#pragma unroll
      for (int it = 0; it < 8; ++it) {
        int r = ar + 16 * it;
        h4v hv;
        hv[0] = (_Float16)fmaxf(apf[it].x + w.x, 0.f);
        hv[1] = (_Float16)fmaxf(apf[it].y + w.y, 0.f);
        hv[2] = (_Float16)fmaxf(apf[it].z + w.z, 0.f);
        hv[3] = (_Float16)fmaxf(apf[it].w + w.w, 0.f);
        *(h4v*)&Ah[r * DST + ac4] = hv;
      }
    }
#pragma unroll
    for (int it = 0; it < 4; ++it)
      *(h8v*)&Bh[(br + 32 * it) * DST + bg] = bpf[it];
    __syncthreads();
    if (hc < 6) {
      const int hn = (hc + 1) * 64;
#pragma unroll
      for (int it = 0; it < 8; ++it)
        apf[it] = *(const float4*)&aptr[(16 * it) * 448 + hn];
    }
#pragma unroll
    for (int kk = 0; kk < 4; ++kk) {
      const int ko = kk * 16 + kg * 8;
      h8v a0 = *(const h8v*)&Ah[(wn * 64 + ln) * DST + ko];
      h8v a1 = *(const h8v*)&Ah[(wn * 64 + 32 + ln) * DST + ko];
      h8v b0 = *(const h8v*)&Bh[(wo * 64 + ln) * DST + ko];
      h8v b1 = *(const h8v*)&Bh[(wo * 64 + 32 + ln) * DST + ko];
      if (full) {
        acc[0][0] = __builtin_amdgcn_mfma_f32_32x32x16_f16(a0, b0, acc[0][0], 0, 0, 0);
        acc[1][0] = __builtin_amdgcn_mfma_f32_32x32x16_f16(a1, b0, acc[1][0], 0, 0, 0);
        acc[0][1] = __builtin_amdgcn_mfma_f32_32x32x16_f16(a0, b1, acc[0][1], 0, 0, 0);
        acc[1][1] = __builtin_amdgcn_mfma_f32_32x32x16_f16(a1, b1, acc[1][1], 0, 0, 0);
      } else if (wo == 0) {
        acc[0][0] = __builtin_amdgcn_mfma_f32_32x32x16_f16(a0, b0, acc[0][0], 0, 0, 0);
        acc[1][0] = __builtin_amdgcn_mfma_f32_32x32x16_f16(a1, b0, acc[1][0], 0, 0, 0);
      }
    }
  }
  const int obase = o0 + wo * 64;
  const float bj0 = (obase + ln < 784) ? decb[obase + ln] : 0.f;
  const float bj1 = (obase + 32 + ln < 784) ? decb[obase + 32 + ln] : 0.f;
#pragma unroll
  for (int i = 0; i < 2; ++i) {
#pragma unroll
    for (int reg = 0; reg < 16; ++reg) {
      const int row = wn * 64 + i * 32 + (reg & 3) + 8 * (reg >> 2) + 4 * kg;
      float v = 0.f;
#pragma unroll
      for (int j = 0; j < 2; ++j) {
        const int o = obase + j * 32 + ln;
        if (o < 784) {
          float x = acc[i][j][reg] + (j ? bj1 : bj0);
          float yv = y[(n0 + row) * 784 + o];
          float spx = fmaxf(x, 0.f) + __logf(1.f + __expf(-fabsf(x)));
          float t2 = fminf(spx, 100.f);
          float t1 = fminf(spx - x, 100.f);
          v += t2 + yv * (t1 - t2);
        }
      }
      v += __shfl_xor(v, 1, 64);
      v += __shfl_xor(v, 2, 64);
      v += __shfl_xor(v, 4, 64);
      v += __shfl_xor(v, 8, 64);
      v += __shfl_xor(v, 16, 64);
      if (ln == 0) red[wo * 128 + row] = v;
    }
  }
  __syncthreads();
  if (tid < 128) {
    float s = red[tid] + red[128 + tid];
    atomicAdd(&lb[(n0 + tid) * 16 + k], s);
  }
}

// ---------------- K5: HMM fwd/bwd + gamma + xi (fused) ----------------
__global__ __launch_bounds__(256, 2)
void k_hmm(const float* __restrict__ lb, const float* __restrict__ lpi,
           const float* __restrict__ lA, float* __restrict__ out) {
  __shared__ float btl[128 * 16];
  __shared__ float ah[128 * 16];
  __shared__ float bh[128 * 16];
  __shared__ float braw[128 * 16];
  __shared__ float A_l[16 * 17];
  __shared__ float pi_l[16];
  __shared__ float sinv_l[128];
  const int tid = threadIdx.x;
  const int b = blockIdx.x;

  for (int idx = tid; idx < 512; idx += 256) {
    float4 v = *(const float4*)&lb[b * 2048 + idx * 4];
    v.x *= -0.01f; v.y *= -0.01f; v.z *= -0.01f; v.w *= -0.01f;
    *(float4*)&btl[idx * 4] = v;
  }
  if (tid < 16) {
    const int j = tid;
    float m = -1e30f;
#pragma unroll
    for (int q = 0; q < 16; ++q) m = fmaxf(m, lA[j * 16 + q]);
    float e[16]; float s = 0.f;
#pragma unroll
    for (int q = 0; q < 16; ++q) { e[q] = expf(lA[j * 16 + q] - m); s += e[q]; }
    float inv = 1.f / s;
#pragma unroll
    for (int q = 0; q < 16; ++q) A_l[j * 17 + q] = e[q] * inv + 1e-9f;
  } else if (tid == 16) {
    float m = -1e30f;
#pragma unroll
    for (int q = 0; q < 16; ++q) m = fmaxf(m, lpi[q]);
    float e[16]; float s = 0.f;
#pragma unroll
    for (int q = 0; q < 16; ++q) { e[q] = expf(lpi[q] - m); s += e[q]; }
    float inv = 1.f / s;
#pragma unroll
    for (int q = 0; q < 16; ++q) pi_l[q] = e[q] * inv + 1e-9f;
  }
  __syncthreads();
  if (tid < 128) {
    const int t = tid;
    float v[16]; float m = -1e30f;
#pragma unroll
    for (int q = 0; q < 16; ++q) { v[q] = btl[t * 16 + q]; m = fmaxf(m, v[q]); }
#pragma unroll
    for (int q = 0; q < 16; ++q) btl[t * 16 + q] = expf(v[q] - m);
  }
  __syncthreads();
  const int lane = tid & 63;
  const int kk = lane & 15, grp = lane >> 4;
  if (tid < 64) {
    float v0 = pi_l[kk] * btl[kk];
    float ss0 = v0;
    ss0 += __shfl_xor(ss0, 1, 64); ss0 += __shfl_xor(ss0, 2, 64);
    ss0 += __shfl_xor(ss0, 4, 64); ss0 += __shfl_xor(ss0, 8, 64);
    if (grp == 0) ah[kk] = v0 / ss0;
    for (int t = 1; t < 128; ++t) {
      float acc = 0.f;
#pragma unroll
      for (int jj = 0; jj < 4; ++jj) {
        int j = grp * 4 + jj;
        acc = fmaf(ah[(t - 1) * 16 + j], A_l[j * 17 + kk], acc);
      }
      acc += __shfl_xor(acc, 16, 64);
      acc += __shfl_xor(acc, 32, 64);
      float v = acc * btl[t * 16 + kk];
      float ss = v;
      ss += __shfl_xor(ss, 1, 64); ss += __shfl_xor(ss, 2, 64);
      ss += __shfl_xor(ss, 4, 64); ss += __shfl_xor(ss, 8, 64);
      if (grp == 0) ah[t * 16 + kk] = v / ss;
    }
  } else if (tid < 128) {
    if (grp == 0) bh[127 * 16 + kk] = 1.f;
    for (int t = 126; t >= 0; --t) {
      float acc = 0.f;
#pragma unroll
      for (int q = 0; q < 4; ++q) {
        int k2 = grp * 4 + q;
        acc = fmaf(A_l[kk * 17 + k2], btl[(t + 1) * 16 + k2] * bh[(t + 1) * 16 + k2], acc);
      }
      acc += __shfl_xor(acc, 16, 64);
      acc += __shfl_xor(acc, 32, 64);
      float ss = acc;
      ss += __shfl_xor(ss, 1, 64); ss += __shfl_xor(ss, 2, 64);
      ss += __shfl_xor(ss, 4, 64); ss += __shfl_xor(ss, 8, 64);
      if (grp == 0) { braw[t * 16 + kk] = acc; bh[t * 16 + kk] = acc / ss; }
    }
  }
  __syncthreads();
  if (tid < 128) {
    const int t = tid;
    float g[16]; float s2 = 0.f;
#pragma unroll
    for (int q = 0; q < 16; ++q) { g[q] = ah[t * 16 + q] * bh[t * 16 + q]; s2 += g[q]; }
    float inv = 1.f / s2;
#pragma unroll
    for (int c = 0; c < 4; ++c) {
      float4 o;
      o.x = g[c * 4 + 0] * inv; o.y = g[c * 4 + 1] * inv;
      o.z = g[c * 4 + 2] * inv; o.w = g[c * 4 + 3] * inv;
      *(float4*)&out[(b * 128 + t) * 16 + c * 4] = o;
    }
  } else {
    const int t = tid - 128;
    if (t < 127) {
      float s2 = 0.f;
#pragma unroll
      for (int q = 0; q < 16; ++q) s2 += ah[t * 16 + q] * braw[t * 16 + q];
      sinv_l[t] = 1.f / s2;
    }
  }
  __syncthreads();
  const int j = tid >> 4, k2 = tid & 15;
  const float aj = A_l[j * 17 + k2];
  float* xo = out + 65536 + (size_t)b * 127 * 256 + tid;
  for (int t = 0; t < 127; ++t) {
    float val = ah[t * 16 + j] * aj * btl[(t + 1) * 16 + k2] *
                bh[(t + 1) * 16 + k2] * sinv_l[t];
    xo[t * 256] = val;
  }
}

extern "C" void kernel_launch(void* const* d_in, const int* in_sizes, int n_in,
                              void* d_out, int out_size, void* d_ws, size_t ws_size,
                              hipStream_t stream) {
  (void)in_sizes; (void)n_in; (void)out_size;
  const float* y   = (const float*)d_in[0];
  const float* ew1 = (const float*)d_in[1];
  const float* eb1 = (const float*)d_in[2];
  const float* ew2 = (const float*)d_in[3];
  const float* eb2 = (const float*)d_in[4];
  const float* dfw = (const float*)d_in[5];
  const float* dfb = (const float*)d_in[6];
  const float* dw  = (const float*)d_in[7];
  const float* db  = (const float*)d_in[8];
  const float* lpi = (const float*)d_in[9];
  const float* lA  = (const float*)d_in[10];
  const float* eps = (const float*)d_in[11];
  float* out = (float*)d_out;

  float* ws = (float*)d_ws;
  float* h      = ws;                 // then reused as basep (fallback path)
  float* basep  = ws;
  float* z      = ws + 1835008;
  float* lb     = z + 65536;
  _Float16* dwh = (_Float16*)(lb + 65536);    // 896*448 halves
  _Float16* w1h = dwh + 896 * 448;            // 512*800 halves
  float* gpad   = (float*)(w1h + 512 * 800);  // legacy g_* region (unused)
  _Float16* hkh = (_Float16*)(gpad + 65536 * 2 + 4096 + 256);  // 58.7 MB
  // yh aliases hkh: written by k_prep, last read by k_enc1, BEFORE k_basehk
  // writes hkh (same stream -> ordered). 6.55MB << 58.7MB region.
  _Float16* yh  = hkh;

  const bool big_ws = (ws_size >= 68748288ull);

  if (big_ws) {
    k_prep<<<15968, 256, 0, stream>>>(dw, ew1, y, dwh, w1h, yh, lb);
    k_enc1<<<dim3(4, 64), 256, 0, stream>>>(yh, w1h, eb1, h);
    k_enc2z<<<256, 128, 0, stream>>>(h, ew2, eb2, eps, z);
    k_basehk<<<256, 256, 0, stream>>>(z, dfw, dfb, hkh);
    k_dec6<<<3584, 256, 0, stream>>>(hkh, dwh, db, y, lb);
  } else {
    k_prep<<<3168, 256, 0, stream>>>(dw, ew1, y, dwh, w1h, yh, lb);
    k_enc1f<<<dim3(4, 64), 256, 0, stream>>>(y, w1h, eb1, h);
    k_enc2z<<<256, 128, 0, stream>>>(h, ew2, eb2, eps, z);
    k_base<<<256, 256, 0, stream>>>(z, dfw, dfb, basep);
    k_dec1<<<3584, 256, 0, stream>>>(basep, dfw, dwh, db, y, lb);
  }
  k_hmm<<<32, 256, 0, stream>>>(lb, lpi, lA, out);
}

// Round 10
// 327.322 us; speedup vs baseline: 1.1119x; 1.1119x over previous
//
#include <hip/hip_runtime.h>
#include <math.h>

// Problem constants (B=32, T=128, K=16, L=16); N = 4096 tokens, 784 pixels, hidden 400.
// Precision strategy: all GEMMs single-term fp16 MFMA with fp32 accumulate.
// Pipeline:
//   k_prep  : decw -> fp16 [896][448]; enc w1 -> fp16 [512][832]; y -> fp16
//             yh[4096][832] (aliased onto hkh region); zero lb
//   k_enc1  : h = relu(y @ W1^T + b1). 13 K-phases of 64 (was 25 of 32 - half
//             the barrier drains), champion's XOR-swizzle LDS (stride 64,
//             store slot = c^((row&7)*8), read cx = kk*16 ^ e0).
//   k_enc2z : z[4096,16]
//   k_basehk: base[16n][448] in LDS -> hkh[16][4096][448] fp16 (fused)
//   k_dec2  : CHAMPION, untouched (147us): 128x128 tile, 33.8KB LDS ->
//             4 blk/CU, {barrier; 8 gll; barrier; MFMA}. Structural variants
//             all lost: A-only dbuf (R5,165), dbuf+1-barrier (R7,198),
//             B-in-regs (R9,188 - 896B lane stride = uncoalesced L2).
//             Occupancy ladder 4blk=145/3blk=165/2blk=198; MFMA-busy ~21us
//             constant. SQ_LDS_BANK_CONFLICT ~6.4M = gll-burst artifact.
//   k_hmm   : fwd/bwd + gamma + xi fused
//   fallback path (small ws): k_enc1f (f32 y) + k_base + k_dec1.

typedef _Float16 h8v __attribute__((ext_vector_type(8)));   // MFMA A/B frag (4 VGPRs)
typedef _Float16 h4v __attribute__((ext_vector_type(4)));
typedef float f16v __attribute__((ext_vector_type(16)));    // MFMA C/D frag

__device__ __forceinline__ void gll16(const void* g, void* l) {
  __builtin_amdgcn_global_load_lds(
      (const __attribute__((address_space(1))) void*)g,
      (__attribute__((address_space(3))) void*)l, 16, 0, 0);
}

// ---------------- k_prep ----------------
// big grid 16544 blocks: lb(64K) + dwh(401408) + w1h(512*832) + yh(4096*832)
__global__ __launch_bounds__(256)
void k_prep(const float* __restrict__ dw, const float* __restrict__ ew1,
            const float* __restrict__ y, _Float16* __restrict__ dwh,
            _Float16* __restrict__ w1h, _Float16* __restrict__ yh,
            float* __restrict__ lb) {
  int idx = blockIdx.x * 256 + threadIdx.x;
  if (idx < 65536) lb[idx] = 0.f;   // zero BCE accumulator (k_dec atomicAdds into it)
  if (idx < 896 * 448) {
    int o = idx / 448, h2 = idx - o * 448;
    float v = (o < 784 && h2 < 400) ? dw[o * 400 + h2] : 0.f;
    dwh[idx] = (_Float16)v;
  } else if (idx < 827392) {                    // 401408 + 512*832
    int j = idx - 401408;
    int i = j / 832, kc = j - i * 832;
    float v = (i < 400 && kc < 784) ? ew1[i * 784 + kc] : 0.f;
    w1h[j] = (_Float16)v;
  } else if (idx < 4235264) {                   // + 4096*832
    int j = idx - 827392;
    int n = j / 832, c = j - n * 832;
    float v = (c < 784) ? y[n * 784 + c] : 0.f;
    yh[j] = (_Float16)v;
  }
}

// ---------------- K1: h = relu(y @ W1^T + b1), 13 phases K=64, XOR-swz LDS ---
__global__ __launch_bounds__(256, 2)
void k_enc1(const _Float16* __restrict__ yh, const _Float16* __restrict__ w1h,
            const float* __restrict__ b1, float* __restrict__ hout) {
  __shared__ __align__(16) _Float16 Ah[64 * 64];    // 8KB
  __shared__ __align__(16) _Float16 Bh[128 * 64];   // 16KB
  const int tid = threadIdx.x;
  const int i0 = blockIdx.x * 128;
  const int n0 = blockIdx.y * 64;
  const int wav = tid >> 6, lane = tid & 63;
  const int wn = wav >> 1, wi = wav & 1;
  const int ln = lane & 31, kg = lane >> 5;

  f16v acc[2];
#pragma unroll
  for (int j = 0; j < 2; ++j)
#pragma unroll
    for (int r = 0; r < 16; ++r) acc[j][r] = 0.f;

  const int sr = tid >> 2;             // staging row (A: 64 rows; B: +64*it)
  const int sc = (tid & 3) * 8;        // staging col chunks: sc, sc+32
  const int e0 = (kg * 8) ^ ((ln & 7) * 8);   // read-side swizzle (champion)

#pragma unroll 1
  for (int hc = 0; hc < 13; ++hc) {
    const int h0 = hc * 64;
    __syncthreads();
    // A: 64x64 halves; swizzled store slot = c ^ ((row&7)*8); 16B aligned.
    {
      const int rs = (sr & 7) * 8;
      *(h8v*)&Ah[sr * 64 + (sc ^ rs)] =
          *(const h8v*)&yh[(n0 + sr) * 832 + h0 + sc];
      *(h8v*)&Ah[sr * 64 + ((sc + 32) ^ rs)] =
          *(const h8v*)&yh[(n0 + sr) * 832 + h0 + sc + 32];
    }
    // B: 128x64 halves
#pragma unroll
    for (int it = 0; it < 2; ++it) {
      const int r = sr + 64 * it;
      const int rs = (r & 7) * 8;
      *(h8v*)&Bh[r * 64 + (sc ^ rs)] =
          *(const h8v*)&w1h[(i0 + r) * 832 + h0 + sc];
      *(h8v*)&Bh[r * 64 + ((sc + 32) ^ rs)] =
          *(const h8v*)&w1h[(i0 + r) * 832 + h0 + sc + 32];
    }
    __syncthreads();
#pragma unroll
    for (int kk = 0; kk < 4; ++kk) {
      const int cx = (kk * 16) ^ e0;
      h8v a  = *(const h8v*)&Ah[(wn * 32 + ln) * 64 + cx];
      h8v b0 = *(const h8v*)&Bh[(wi * 64 + ln) * 64 + cx];
      h8v b1 = *(const h8v*)&Bh[(wi * 64 + 32 + ln) * 64 + cx];
      acc[0] = __builtin_amdgcn_mfma_f32_32x32x16_f16(a, b0, acc[0], 0, 0, 0);
      acc[1] = __builtin_amdgcn_mfma_f32_32x32x16_f16(a, b1, acc[1], 0, 0, 0);
    }
  }
#pragma unroll
  for (int j = 0; j < 2; ++j) {
    const int i = i0 + wi * 64 + j * 32 + ln;
    if (i < 400) {
      const float bias = b1[i];
#pragma unroll
      for (int reg = 0; reg < 16; ++reg) {
        const int row = n0 + wn * 32 + (reg & 3) + 8 * (reg >> 2) + 4 * kg;
        hout[row * 400 + i] = fmaxf(acc[j][reg] + bias, 0.f);
      }
    }
  }
}

// ---------------- K1 fallback: f32 y input (small-ws path) -------------------
#define E1ST 40
__global__ __launch_bounds__(256, 2)
void k_enc1f(const float* __restrict__ y, const _Float16* __restrict__ w1h,
             const float* __restrict__ b1, float* __restrict__ hout) {
  __shared__ __align__(16) _Float16 Ah[64 * E1ST];
  __shared__ __align__(16) _Float16 Bh[128 * E1ST];
  const int tid = threadIdx.x;
  const int i0 = blockIdx.x * 128;
  const int n0 = blockIdx.y * 64;
  const int wav = tid >> 6, lane = tid & 63;
  const int wn = wav >> 1, wi = wav & 1;
  const int ln = lane & 31, kg = lane >> 5;

  f16v acc[2];
#pragma unroll
  for (int j = 0; j < 2; ++j)
#pragma unroll
    for (int r = 0; r < 16; ++r) acc[j][r] = 0.f;

  const int ar = tid >> 3, ac4 = (tid & 7) * 4;
  const int br = tid >> 2, bg = (tid & 3) * 8;

#pragma unroll 1
  for (int hc = 0; hc < 25; ++hc) {
    const int h0 = hc * 32;
    __syncthreads();
#pragma unroll
    for (int it = 0; it < 2; ++it) {
      int r = ar + 32 * it;
      float4 a = make_float4(0.f, 0.f, 0.f, 0.f);
      if (h0 + ac4 < 784) a = *(const float4*)&y[(n0 + r) * 784 + h0 + ac4];
      h4v hv;
      hv[0] = (_Float16)a.x; hv[1] = (_Float16)a.y;
      hv[2] = (_Float16)a.z; hv[3] = (_Float16)a.w;
      *(h4v*)&Ah[r * E1ST + ac4] = hv;
    }
#pragma unroll
    for (int it = 0; it < 2; ++it) {
      int r = br + 64 * it;
      *(h8v*)&Bh[r * E1ST + bg] = *(const h8v*)&w1h[(i0 + r) * 800 + h0 + bg];
    }
    __syncthreads();
#pragma unroll
    for (int kk = 0; kk < 2; ++kk) {
      const int ko = kk * 16 + kg * 8;
      h8v a  = *(const h8v*)&Ah[(wn * 32 + ln) * E1ST + ko];
      h8v b0 = *(const h8v*)&Bh[(wi * 64 + ln) * E1ST + ko];
      h8v b1 = *(const h8v*)&Bh[(wi * 64 + 32 + ln) * E1ST + ko];
      acc[0] = __builtin_amdgcn_mfma_f32_32x32x16_f16(a, b0, acc[0], 0, 0, 0);
      acc[1] = __builtin_amdgcn_mfma_f32_32x32x16_f16(a, b1, acc[1], 0, 0, 0);
    }
  }
#pragma unroll
  for (int j = 0; j < 2; ++j) {
    const int i = i0 + wi * 64 + j * 32 + ln;
    if (i < 400) {
      const float bias = b1[i];
#pragma unroll
      for (int reg = 0; reg < 16; ++reg) {
        const int row = n0 + wn * 32 + (reg & 3) + 8 * (reg >> 2) + 4 * kg;
        hout[row * 400 + i] = fmaxf(acc[j][reg] + bias, 0.f);
      }
    }
  }
}

// ---------------- K2: ml = h @ W2^T + b2, z = mu + eps*exp(0.5*logvar) --------
__global__ __launch_bounds__(128, 2)
void k_enc2z(const float* __restrict__ h, const float* __restrict__ w2,
             const float* __restrict__ b2, const float* __restrict__ eps,
             float* __restrict__ z) {
  __shared__ __align__(16) float h_lds[16 * 400];
  __shared__ __align__(16) float w2_lds[32 * 404];
  __shared__ float ml_lds[16 * 32];
  const int tid = threadIdx.x;
  const int n0 = blockIdx.x * 16;
  for (int idx = tid; idx < 1600; idx += 128) {
    int r = idx / 100, c = idx - r * 100;
    *(float4*)&h_lds[r * 400 + c * 4] = *(const float4*)&h[(n0 + r) * 400 + c * 4];
  }
  for (int idx = tid; idx < 3200; idx += 128) {
    int r = idx / 100, c = idx - r * 100;
    *(float4*)&w2_lds[r * 404 + c * 4] = *(const float4*)&w2[r * 400 + c * 4];
  }
  __syncthreads();
  const int c_ = tid & 31, n4 = tid >> 5;
  float a0 = 0.f, a1 = 0.f, a2 = 0.f, a3 = 0.f;
  for (int q = 0; q < 100; ++q) {
    float4 wv = *(const float4*)&w2_lds[c_ * 404 + q * 4];
    float4 h0 = *(const float4*)&h_lds[(n4 * 4 + 0) * 400 + q * 4];
    float4 h1 = *(const float4*)&h_lds[(n4 * 4 + 1) * 400 + q * 4];
    float4 h2 = *(const float4*)&h_lds[(n4 * 4 + 2) * 400 + q * 4];
    float4 h3 = *(const float4*)&h_lds[(n4 * 4 + 3) * 400 + q * 4];
    a0 += h0.x * wv.x + h0.y * wv.y + h0.z * wv.z + h0.w * wv.w;
    a1 += h1.x * wv.x + h1.y * wv.y + h1.z * wv.z + h1.w * wv.w;
    a2 += h2.x * wv.x + h2.y * wv.y + h2.z * wv.z + h2.w * wv.w;
    a3 += h3.x * wv.x + h3.y * wv.y + h3.z * wv.z + h3.w * wv.w;
  }
  const float bb = b2[c_];
  ml_lds[(n4 * 4 + 0) * 32 + c_] = a0 + bb;
  ml_lds[(n4 * 4 + 1) * 32 + c_] = a1 + bb;
  ml_lds[(n4 * 4 + 2) * 32 + c_] = a2 + bb;
  ml_lds[(n4 * 4 + 3) * 32 + c_] = a3 + bb;
  __syncthreads();
  for (int t = tid; t < 256; t += 128) {
    int n2 = t >> 4, l = t & 15;
    float mu = ml_lds[n2 * 32 + l];
    float lv = ml_lds[n2 * 32 + 16 + l];
    z[(n0 + n2) * 16 + l] = mu + eps[(n0 + n2) * 16 + l] * expf(0.5f * lv);
  }
}

// ---------------- k_basehk: fused base + hk (big-ws path) --------------------
__global__ __launch_bounds__(256, 2)
void k_basehk(const float* __restrict__ z, const float* __restrict__ dfw,
              const float* __restrict__ dfb, _Float16* __restrict__ hkh) {
  __shared__ float z_lds[16 * 16];
  __shared__ __align__(16) float wz[400 * 20];   // phase1: Wz rows; phase2: wxT[16][448]
  __shared__ __align__(16) float base[16 * 448];
  const int tid = threadIdx.x;
  const int n0 = blockIdx.x * 16;
  if (tid < 64) {
    int n = tid >> 2, c = (tid & 3) * 4;
    *(float4*)&z_lds[n * 16 + c] = *(const float4*)&z[(n0 + n) * 16 + c];
  }
  for (int idx = tid; idx < 1600; idx += 256) {
    int i = idx >> 2, c = (idx & 3) * 4;
    *(float4*)&wz[i * 20 + c] = *(const float4*)&dfw[i * 32 + c];
  }
  __syncthreads();
  for (int idx = tid; idx < 7168; idx += 256) {
    int n = idx / 448, i = idx - n * 448;
    float acc = 0.f;
    if (i < 400) {
      acc = dfb[i];
#pragma unroll
      for (int q = 0; q < 4; ++q) {
        float4 zv = *(const float4*)&z_lds[n * 16 + q * 4];
        float4 wv = *(const float4*)&wz[i * 20 + q * 4];
        acc += zv.x * wv.x + zv.y * wv.y + zv.z * wv.z + zv.w * wv.w;
      }
    }
    base[n * 448 + i] = acc;
  }
  __syncthreads();
  for (int idx = tid; idx < 7168; idx += 256) {
    int k = idx / 448, hh = idx - k * 448;
    wz[idx] = (hh < 400) ? dfw[hh * 32 + 16 + k] : 0.f;
  }
  __syncthreads();
  for (int s = tid; s < 14336; s += 256) {
    int k = s / 896, r2 = s - k * 896;
    int r = r2 / 56, c8 = r2 - r * 56;
    const float* bp = &base[r * 448 + c8 * 8];
    const float* wp = &wz[k * 448 + c8 * 8];
    float4 b0 = *(const float4*)bp, b1 = *(const float4*)(bp + 4);
    float4 w0 = *(const float4*)wp, w1 = *(const float4*)(wp + 4);
    h8v o;
    o[0] = (_Float16)fmaxf(b0.x + w0.x, 0.f);
    o[1] = (_Float16)fmaxf(b0.y + w0.y, 0.f);
    o[2] = (_Float16)fmaxf(b0.z + w0.z, 0.f);
    o[3] = (_Float16)fmaxf(b0.w + w0.w, 0.f);
    o[4] = (_Float16)fmaxf(b1.x + w1.x, 0.f);
    o[5] = (_Float16)fmaxf(b1.y + w1.y, 0.f);
    o[6] = (_Float16)fmaxf(b1.z + w1.z, 0.f);
    o[7] = (_Float16)fmaxf(b1.w + w1.w, 0.f);
    *(h8v*)&hkh[((size_t)k * 4096 + n0 + r) * 448 + c8 * 8] = o;
  }
}

// ---------------- K3 (fallback path): base_p = z @ Wz^T + dec_fc_b -----------
__global__ __launch_bounds__(256, 4)
void k_base(const float* __restrict__ z, const float* __restrict__ dfw,
            const float* __restrict__ dfb, float* __restrict__ basep) {
  __shared__ float z_lds[16 * 16];
  __shared__ __align__(16) float wz_lds[400 * 20];
  const int tid = threadIdx.x;
  const int n0 = blockIdx.x * 16;
  if (tid < 64) {
    int n = tid >> 2, c = (tid & 3) * 4;
    *(float4*)&z_lds[n * 16 + c] = *(const float4*)&z[(n0 + n) * 16 + c];
  }
  for (int idx = tid; idx < 1600; idx += 256) {
    int i = idx >> 2, c = (idx & 3) * 4;
    *(float4*)&wz_lds[i * 20 + c] = *(const float4*)&dfw[i * 32 + c];
  }
  __syncthreads();
  for (int idx = tid; idx < 7168; idx += 256) {
    int n = idx / 448, i = idx - n * 448;
    float acc = 0.f;
    if (i < 400) {
      acc = dfb[i];
#pragma unroll
      for (int q = 0; q < 4; ++q) {
        float4 zv = *(const float4*)&z_lds[n * 16 + q * 4];
        float4 wv = *(const float4*)&wz_lds[i * 20 + q * 4];
        acc += zv.x * wv.x + zv.y * wv.y + zv.z * wv.z + zv.w * wv.w;
      }
    }
    basep[(n0 + n) * 448 + i] = acc;
  }
}

// ---------------- K4: R4 champion k_dec2 (147us, UNCHANGED) ----------------
__global__ __launch_bounds__(256, 2)
void k_dec2(const _Float16* __restrict__ hkh, const _Float16* __restrict__ dwh,
            const float* __restrict__ decb, const float* __restrict__ y,
            float* __restrict__ lb) {
  __shared__ __align__(16) _Float16 Ah[128 * 64];
  __shared__ __align__(16) _Float16 Bh[128 * 64];
  __shared__ float red[256];

  const int tid = threadIdx.x;
  const int id  = blockIdx.x;
  const int lin = (id & 7) * 448 + (id >> 3);   // 3584 = 8 XCD x 448, bijective
  const int n_i = lin / 112;
  const int rem = lin - n_i * 112;
  const int k   = rem / 7;
  const int ot  = rem - k * 7;
  const int n0  = n_i * 128;
  const int o0  = ot * 128;

  const int wav = tid >> 6, lane = tid & 63;
  const int wn = wav >> 1, wo = wav & 1;
  const int ln = lane & 31, kg = lane >> 5;

  const int l8 = lane >> 3, l7 = lane & 7;
  const int swh = (l7 * 8) ^ (l8 * 8);
  const _Float16* hkk = hkh + (size_t)k * (4096 * 448);
  const _Float16* pA[4];
  const _Float16* pB[4];
#pragma unroll
  for (int i = 0; i < 4; ++i) {
    const int row = wav * 32 + i * 8 + l8;
    pA[i] = hkk + (size_t)(n0 + row) * 448 + swh;
    pB[i] = dwh + (size_t)(o0 + row) * 448 + swh;
  }

  f16v acc[2][2];
#pragma unroll
  for (int i = 0; i < 2; ++i)
#pragma unroll
    for (int j = 0; j < 2; ++j)
#pragma unroll
      for (int r = 0; r < 16; ++r) acc[i][j][r] = 0.f;

  const int sx = (ln & 7) * 8;          // read-side swizzle
  const int e0 = (kg * 8) ^ sx;
  const int arow = (wn * 64 + ln) * 64;
  const int brow = (wo * 64 + ln) * 64;

#pragma unroll 1
  for (int hc = 0; hc < 7; ++hc) {
    __syncthreads();                    // previous phase done reading LDS
#pragma unroll
    for (int i = 0; i < 4; ++i) {
      gll16(pA[i], &Ah[(wav * 4 + i) * 512]);
      gll16(pB[i], &Bh[(wav * 4 + i) * 512]);
      pA[i] += 64; pB[i] += 64;
    }
    __syncthreads();                    // drains vmcnt -> LDS tiles ready
#pragma unroll
    for (int kk = 0; kk < 4; ++kk) {
      const int cx = (kk * 16) ^ e0;    // slot = logical col ^ swizzle
      h8v a0 = *(const h8v*)&Ah[arow + cx];
      h8v a1 = *(const h8v*)&Ah[arow + 2048 + cx];
      h8v b0 = *(const h8v*)&Bh[brow + cx];
      h8v b1 = *(const h8v*)&Bh[brow + 2048 + cx];
      acc[0][0] = __builtin_amdgcn_mfma_f32_32x32x16_f16(a0, b0, acc[0][0], 0, 0, 0);
      acc[1][0] = __builtin_amdgcn_mfma_f32_32x32x16_f16(a1, b0, acc[1][0], 0, 0, 0);
      acc[0][1] = __builtin_amdgcn_mfma_f32_32x32x16_f16(a0, b1, acc[0][1], 0, 0, 0);
      acc[1][1] = __builtin_amdgcn_mfma_f32_32x32x16_f16(a1, b1, acc[1][1], 0, 0, 0);
    }
  }
  // epilogue: fused BCE. clip-at-100 provably dead (|x|<=~10).
  const int obase = o0 + wo * 64;
  const float bj0 = (obase + ln < 784) ? decb[obase + ln] : 0.f;
  const float bj1 = (obase + 32 + ln < 784) ? decb[obase + 32 + ln] : 0.f;
#pragma unroll
  for (int i = 0; i < 2; ++i) {
#pragma unroll
    for (int reg = 0; reg < 16; ++reg) {
      const int row = wn * 64 + i * 32 + (reg & 3) + 8 * (reg >> 2) + 4 * kg;
      float v = 0.f;
#pragma unroll
      for (int j = 0; j < 2; ++j) {
        const int o = obase + j * 32 + ln;
        if (o < 784) {
          float x = acc[i][j][reg] + (j ? bj1 : bj0);
          float yv = y[(n0 + row) * 784 + o];
          float spx = fmaxf(x, 0.f) + __logf(1.f + __expf(-fabsf(x)));
          v += spx - yv * x;
        }
      }
      v += __shfl_xor(v, 1, 64);
      v += __shfl_xor(v, 2, 64);
      v += __shfl_xor(v, 4, 64);
      v += __shfl_xor(v, 8, 64);
      v += __shfl_xor(v, 16, 64);
      if (ln == 0) red[wo * 128 + row] = v;
    }
  }
  __syncthreads();
  if (tid < 128) {
    float s = red[tid] + red[128 + tid];
    atomicAdd(&lb[(n0 + tid) * 16 + k], s);
  }
}

// ---------------- K4 v1 (fallback if ws too small for hkh) -------------------
#define DST 72
__global__ __launch_bounds__(256, 2)
void k_dec1(const float* __restrict__ basep, const float* __restrict__ dfw,
            const _Float16* __restrict__ dwh, const float* __restrict__ decb,
            const float* __restrict__ y, float* __restrict__ lb) {
  __shared__ __align__(16) _Float16 Ah[128 * DST];
  __shared__ __align__(16) _Float16 Bh[128 * DST];
  __shared__ float wx[448];
  __shared__ float red[256];

  const int tid = threadIdx.x;
  const int id  = blockIdx.x;
  const int lin = (id & 7) * 448 + (id >> 3);
  const int n_i = lin / 112;
  const int rem = lin - n_i * 112;
  const int k   = rem / 7;
  const int ot  = rem - k * 7;
  const int n0  = n_i * 128;
  const int o0  = ot * 128;
  const bool full = (ot < 6);

  const int wav = tid >> 6, lane = tid & 63;
  const int wn = wav >> 1, wo = wav & 1;
  const int ln = lane & 31, kg = lane >> 5;

  for (int i = tid; i < 448; i += 256) wx[i] = (i < 400) ? dfw[i * 32 + 16 + k] : 0.f;

  const int ar = tid >> 4, ac4 = (tid & 15) * 4;
  const int br = tid >> 3, bg = (tid & 7) * 8;
  const float* aptr = basep + (long)(n0 + ar) * 448 + ac4;

  float4 apf[8];
#pragma unroll
  for (int it = 0; it < 8; ++it) apf[it] = *(const float4*)&aptr[(16 * it) * 448];

  f16v acc[2][2];
#pragma unroll
  for (int i = 0; i < 2; ++i)
#pragma unroll
    for (int j = 0; j < 2; ++j)
#pragma unroll
      for (int r = 0; r < 16; ++r) acc[i][j][r] = 0.f;

#pragma unroll 1
  for (int hc = 0; hc < 7; ++hc) {
    const int h0 = hc * 64;
    h8v bpf[4];
#pragma unroll
    for (int it = 0; it < 4; ++it)
      bpf[it] = *(const h8v*)&dwh[(o0 + br + 32 * it) * 448 + h0 + bg];
    __syncthreads();
    {
      float4 w = *(const float4*)&wx[h0 + ac4];
#pragma unroll
      for (int it = 0; it < 8; ++it) {
        int r = ar + 16 * it;
        h4v hv;
        hv[0] = (_Float16)fmaxf(apf[it].x + w.x, 0.f);
        hv[1] = (_Float16)fmaxf(apf[it].y + w.y, 0.f);
        hv[2] = (_Float16)fmaxf(apf[it].z + w.z, 0.f);
        hv[3] = (_Float16)fmaxf(apf[it].w + w.w, 0.f);
        *(h4v*)&Ah[r * DST + ac4] = hv;
      }
    }
#pragma unroll
    for (int it = 0; it < 4; ++it)
      *(h8v*)&Bh[(br + 32 * it) * DST + bg] = bpf[it];
    __syncthreads();
    if (hc < 6) {
      const int hn = (hc + 1) * 64;
#pragma unroll
      for (int it = 0; it < 8; ++it)
        apf[it] = *(const float4*)&aptr[(16 * it) * 448 + hn];
    }
#pragma unroll
    for (int kk = 0; kk < 4; ++kk) {
      const int ko = kk * 16 + kg * 8;
      h8v a0 = *(const h8v*)&Ah[(wn * 64 + ln) * DST + ko];
      h8v a1 = *(const h8v*)&Ah[(wn * 64 + 32 + ln) * DST + ko];
      h8v b0 = *(const h8v*)&Bh[(wo * 64 + ln) * DST + ko];
      h8v b1 = *(const h8v*)&Bh[(wo * 64 + 32 + ln) * DST + ko];
      if (full) {
        acc[0][0] = __builtin_amdgcn_mfma_f32_32x32x16_f16(a0, b0, acc[0][0], 0, 0, 0);
        acc[1][0] = __builtin_amdgcn_mfma_f32_32x32x16_f16(a1, b0, acc[1][0], 0, 0, 0);
        acc[0][1] = __builtin_amdgcn_mfma_f32_32x32x16_f16(a0, b1, acc[0][1], 0, 0, 0);
        acc[1][1] = __builtin_amdgcn_mfma_f32_32x32x16_f16(a1, b1, acc[1][1], 0, 0, 0);
      } else if (wo == 0) {
        acc[0][0] = __builtin_amdgcn_mfma_f32_32x32x16_f16(a0, b0, acc[0][0], 0, 0, 0);
        acc[1][0] = __builtin_amdgcn_mfma_f32_32x32x16_f16(a1, b0, acc[1][0], 0, 0, 0);
      }
    }
  }
  const int obase = o0 + wo * 64;
  const float bj0 = (obase + ln < 784) ? decb[obase + ln] : 0.f;
  const float bj1 = (obase + 32 + ln < 784) ? decb[obase + 32 + ln] : 0.f;
#pragma unroll
  for (int i = 0; i < 2; ++i) {
#pragma unroll
    for (int reg = 0; reg < 16; ++reg) {
      const int row = wn * 64 + i * 32 + (reg & 3) + 8 * (reg >> 2) + 4 * kg;
      float v = 0.f;
#pragma unroll
      for (int j = 0; j < 2; ++j) {
        const int o = obase + j * 32 + ln;
        if (o < 784) {
          float x = acc[i][j][reg] + (j ? bj1 : bj0);
          float yv = y[(n0 + row) * 784 + o];
          float spx = fmaxf(x, 0.f) + __logf(1.f + __expf(-fabsf(x)));
          float t2 = fminf(spx, 100.f);
          float t1 = fminf(spx - x, 100.f);
          v += t2 + yv * (t1 - t2);
        }
      }
      v += __shfl_xor(v, 1, 64);
      v += __shfl_xor(v, 2, 64);
      v += __shfl_xor(v, 4, 64);
      v += __shfl_xor(v, 8, 64);
      v += __shfl_xor(v, 16, 64);
      if (ln == 0) red[wo * 128 + row] = v;
    }
  }
  __syncthreads();
  if (tid < 128) {
    float s = red[tid] + red[128 + tid];
    atomicAdd(&lb[(n0 + tid) * 16 + k], s);
  }
}

// ---------------- K5: HMM fwd/bwd + gamma + xi (fused) ----------------
__global__ __launch_bounds__(256, 2)
void k_hmm(const float* __restrict__ lb, const float* __restrict__ lpi,
           const float* __restrict__ lA, float* __restrict__ out) {
  __shared__ float btl[128 * 16];
  __shared__ float ah[128 * 16];
  __shared__ float bh[128 * 16];
  __shared__ float braw[128 * 16];
  __shared__ float A_l[16 * 17];
  __shared__ float pi_l[16];
  __shared__ float sinv_l[128];
  const int tid = threadIdx.x;
  const int b = blockIdx.x;

  for (int idx = tid; idx < 512; idx += 256) {
    float4 v = *(const float4*)&lb[b * 2048 + idx * 4];
    v.x *= -0.01f; v.y *= -0.01f; v.z *= -0.01f; v.w *= -0.01f;
    *(float4*)&btl[idx * 4] = v;
  }
  if (tid < 16) {
    const int j = tid;
    float m = -1e30f;
#pragma unroll
    for (int q = 0; q < 16; ++q) m = fmaxf(m, lA[j * 16 + q]);
    float e[16]; float s = 0.f;
#pragma unroll
    for (int q = 0; q < 16; ++q) { e[q] = expf(lA[j * 16 + q] - m); s += e[q]; }
    float inv = 1.f / s;
#pragma unroll
    for (int q = 0; q < 16; ++q) A_l[j * 17 + q] = e[q] * inv + 1e-9f;
  } else if (tid == 16) {
    float m = -1e30f;
#pragma unroll
    for (int q = 0; q < 16; ++q) m = fmaxf(m, lpi[q]);
    float e[16]; float s = 0.f;
#pragma unroll
    for (int q = 0; q < 16; ++q) { e[q] = expf(lpi[q] - m); s += e[q]; }
    float inv = 1.f / s;
#pragma unroll
    for (int q = 0; q < 16; ++q) pi_l[q] = e[q] * inv + 1e-9f;
  }
  __syncthreads();
  if (tid < 128) {
    const int t = tid;
    float v[16]; float m = -1e30f;
#pragma unroll
    for (int q = 0; q < 16; ++q) { v[q] = btl[t * 16 + q]; m = fmaxf(m, v[q]); }
#pragma unroll
    for (int q = 0; q < 16; ++q) btl[t * 16 + q] = expf(v[q] - m);
  }
  __syncthreads();
  const int lane = tid & 63;
  const int kk = lane & 15, grp = lane >> 4;
  if (tid < 64) {
    float v0 = pi_l[kk] * btl[kk];
    float ss0 = v0;
    ss0 += __shfl_xor(ss0, 1, 64); ss0 += __shfl_xor(ss0, 2, 64);
    ss0 += __shfl_xor(ss0, 4, 64); ss0 += __shfl_xor(ss0, 8, 64);
    if (grp == 0) ah[kk] = v0 / ss0;
    for (int t = 1; t < 128; ++t) {
      float acc = 0.f;
#pragma unroll
      for (int jj = 0; jj < 4; ++jj) {
        int j = grp * 4 + jj;
        acc = fmaf(ah[(t - 1) * 16 + j], A_l[j * 17 + kk], acc);
      }
      acc += __shfl_xor(acc, 16, 64);
      acc += __shfl_xor(acc, 32, 64);
      float v = acc * btl[t * 16 + kk];
      float ss = v;
      ss += __shfl_xor(ss, 1, 64); ss += __shfl_xor(ss, 2, 64);
      ss += __shfl_xor(ss, 4, 64); ss += __shfl_xor(ss, 8, 64);
      if (grp == 0) ah[t * 16 + kk] = v / ss;
    }
  } else if (tid < 128) {
    if (grp == 0) bh[127 * 16 + kk] = 1.f;
    for (int t = 126; t >= 0; --t) {
      float acc = 0.f;
#pragma unroll
      for (int q = 0; q < 4; ++q) {
        int k2 = grp * 4 + q;
        acc = fmaf(A_l[kk * 17 + k2], btl[(t + 1) * 16 + k2] * bh[(t + 1) * 16 + k2], acc);
      }
      acc += __shfl_xor(acc, 16, 64);
      acc += __shfl_xor(acc, 32, 64);
      float ss = acc;
      ss += __shfl_xor(ss, 1, 64); ss += __shfl_xor(ss, 2, 64);
      ss += __shfl_xor(ss, 4, 64); ss += __shfl_xor(ss, 8, 64);
      if (grp == 0) { braw[t * 16 + kk] = acc; bh[t * 16 + kk] = acc / ss; }
    }
  }
  __syncthreads();
  if (tid < 128) {
    const int t = tid;
    float g[16]; float s2 = 0.f;
#pragma unroll
    for (int q = 0; q < 16; ++q) { g[q] = ah[t * 16 + q] * bh[t * 16 + q]; s2 += g[q]; }
    float inv = 1.f / s2;
#pragma unroll
    for (int c = 0; c < 4; ++c) {
      float4 o;
      o.x = g[c * 4 + 0] * inv; o.y = g[c * 4 + 1] * inv;
      o.z = g[c * 4 + 2] * inv; o.w = g[c * 4 + 3] * inv;
      *(float4*)&out[(b * 128 + t) * 16 + c * 4] = o;
    }
  } else {
    const int t = tid - 128;
    if (t < 127) {
      float s2 = 0.f;
#pragma unroll
      for (int q = 0; q < 16; ++q) s2 += ah[t * 16 + q] * braw[t * 16 + q];
      sinv_l[t] = 1.f / s2;
    }
  }
  __syncthreads();
  const int j = tid >> 4, k2 = tid & 15;
  const float aj = A_l[j * 17 + k2];
  float* xo = out + 65536 + (size_t)b * 127 * 256 + tid;
  for (int t = 0; t < 127; ++t) {
    float val = ah[t * 16 + j] * aj * btl[(t + 1) * 16 + k2] *
                bh[(t + 1) * 16 + k2] * sinv_l[t];
    xo[t * 256] = val;
  }
}

extern "C" void kernel_launch(void* const* d_in, const int* in_sizes, int n_in,
                              void* d_out, int out_size, void* d_ws, size_t ws_size,
                              hipStream_t stream) {
  (void)in_sizes; (void)n_in; (void)out_size;
  const float* y   = (const float*)d_in[0];
  const float* ew1 = (const float*)d_in[1];
  const float* eb1 = (const float*)d_in[2];
  const float* ew2 = (const float*)d_in[3];
  const float* eb2 = (const float*)d_in[4];
  const float* dfw = (const float*)d_in[5];
  const float* dfb = (const float*)d_in[6];
  const float* dw  = (const float*)d_in[7];
  const float* db  = (const float*)d_in[8];
  const float* lpi = (const float*)d_in[9];
  const float* lA  = (const float*)d_in[10];
  const float* eps = (const float*)d_in[11];
  float* out = (float*)d_out;

  float* ws = (float*)d_ws;
  float* h      = ws;                 // then reused as basep (fallback path)
  float* basep  = ws;
  float* z      = ws + 1835008;
  float* lb     = z + 65536;
  _Float16* dwh = (_Float16*)(lb + 65536);    // 896*448 halves
  _Float16* w1h = dwh + 896 * 448;            // 512*832 halves (big) / 512*800 (fallback)
  float* gpad   = (float*)(w1h + 512 * 832);  // spacer
  _Float16* hkh = (_Float16*)(gpad + 65536 * 2 + 4096 + 256);  // 58.7 MB
  // yh aliases hkh: written by k_prep, last read by k_enc1, BEFORE k_basehk
  // writes hkh (same stream -> ordered). 6.8MB << 58.7MB region.
  _Float16* yh  = hkh;

  const bool big_ws = (ws_size >= 68814848ull);

  if (big_ws) {
    k_prep<<<16544, 256, 0, stream>>>(dw, ew1, y, dwh, w1h, yh, lb);
    k_enc1<<<dim3(4, 64), 256, 0, stream>>>(yh, w1h, eb1, h);
    k_enc2z<<<256, 128, 0, stream>>>(h, ew2, eb2, eps, z);
    k_basehk<<<256, 256, 0, stream>>>(z, dfw, dfb, hkh);
    k_dec2<<<3584, 256, 0, stream>>>(hkh, dwh, db, y, lb);
  } else {
    // fallback: w1h at 800-stride layout
    k_prep<<<3168, 256, 0, stream>>>(dw, ew1, y, dwh, w1h, yh, lb);   // yh branch unreached
    k_enc1f<<<dim3(4, 64), 256, 0, stream>>>(y, w1h, eb1, h);
    k_enc2z<<<256, 128, 0, stream>>>(h, ew2, eb2, eps, z);
    k_base<<<256, 256, 0, stream>>>(z, dfw, dfb, basep);
    k_dec1<<<3584, 256, 0, stream>>>(basep, dfw, dwh, db, y, lb);
  }
  k_hmm<<<32, 256, 0, stream>>>(lb, lpi, lA, out);
}

// Round 11
// 314.350 us; speedup vs baseline: 1.1578x; 1.0413x over previous
//
#include <hip/hip_runtime.h>
#include <math.h>

// Problem constants (B=32, T=128, K=16, L=16); N = 4096 tokens, 784 pixels, hidden 400.
// Precision strategy: all GEMMs single-term fp16 MFMA with fp32 accumulate.
// Pipeline (big-ws path):
//   k_prep : decw -> fp16 [896][448]; enc w1 -> fp16 [512][832]; y -> fp16
//            yh[4096][832] (aliased onto hkh region); zero lb
//   k_enc1 : h = relu(y @ W1^T + b1), 13 K-phases of 64, XOR-swz LDS
//   k_ezbh : FUSED enc2z+basehk (R11): ml -> z in LDS (no global z round-trip,
//            one launch fewer) -> base[16][448] -> hkh[16][4096][448] fp16.
//            141KB LDS; occupancy was already 1 blk/CU (256 blocks/256 CUs).
//   k_dec2 : CHAMPION, untouched (145us, 4x reproduced): 128x128 tile,
//            33.8KB LDS -> 4 blk/CU, {barrier; 8 gll; barrier; MFMA}.
//            Structural variants all lost: A-only dbuf (R5,165), dbuf+
//            1-barrier (R7,198), B-in-regs (R9,188: 896B lane stride =
//            uncoalesced L2). Occupancy ladder 4blk=145/3blk=165/2blk=198;
//            MFMA-busy ~21us constant. BANK_CONFLICT ~6.4M = gll artifact.
//   k_hmm  : fwd/bwd + gamma + xi fused (serial 128-step chain, ~20us floor)
//   fallback (small ws): k_enc1f + k_enc2z + k_base + k_dec1.

typedef _Float16 h8v __attribute__((ext_vector_type(8)));   // MFMA A/B frag (4 VGPRs)
typedef _Float16 h4v __attribute__((ext_vector_type(4)));
typedef float f16v __attribute__((ext_vector_type(16)));    // MFMA C/D frag

__device__ __forceinline__ void gll16(const void* g, void* l) {
  __builtin_amdgcn_global_load_lds(
      (const __attribute__((address_space(1))) void*)g,
      (__attribute__((address_space(3))) void*)l, 16, 0, 0);
}

// ---------------- k_prep ----------------
// big grid 16544 blocks: lb(64K) + dwh(401408) + w1h(512*832) + yh(4096*832)
__global__ __launch_bounds__(256)
void k_prep(const float* __restrict__ dw, const float* __restrict__ ew1,
            const float* __restrict__ y, _Float16* __restrict__ dwh,
            _Float16* __restrict__ w1h, _Float16* __restrict__ yh,
            float* __restrict__ lb) {
  int idx = blockIdx.x * 256 + threadIdx.x;
  if (idx < 65536) lb[idx] = 0.f;   // zero BCE accumulator (k_dec atomicAdds into it)
  if (idx < 896 * 448) {
    int o = idx / 448, h2 = idx - o * 448;
    float v = (o < 784 && h2 < 400) ? dw[o * 400 + h2] : 0.f;
    dwh[idx] = (_Float16)v;
  } else if (idx < 827392) {                    // 401408 + 512*832
    int j = idx - 401408;
    int i = j / 832, kc = j - i * 832;
    float v = (i < 400 && kc < 784) ? ew1[i * 784 + kc] : 0.f;
    w1h[j] = (_Float16)v;
  } else if (idx < 4235264) {                   // + 4096*832
    int j = idx - 827392;
    int n = j / 832, c = j - n * 832;
    float v = (c < 784) ? y[n * 784 + c] : 0.f;
    yh[j] = (_Float16)v;
  }
}

// ---------------- K1: h = relu(y @ W1^T + b1), 13 phases K=64, XOR-swz LDS ---
__global__ __launch_bounds__(256, 2)
void k_enc1(const _Float16* __restrict__ yh, const _Float16* __restrict__ w1h,
            const float* __restrict__ b1, float* __restrict__ hout) {
  __shared__ __align__(16) _Float16 Ah[64 * 64];    // 8KB
  __shared__ __align__(16) _Float16 Bh[128 * 64];   // 16KB
  const int tid = threadIdx.x;
  const int i0 = blockIdx.x * 128;
  const int n0 = blockIdx.y * 64;
  const int wav = tid >> 6, lane = tid & 63;
  const int wn = wav >> 1, wi = wav & 1;
  const int ln = lane & 31, kg = lane >> 5;

  f16v acc[2];
#pragma unroll
  for (int j = 0; j < 2; ++j)
#pragma unroll
    for (int r = 0; r < 16; ++r) acc[j][r] = 0.f;

  const int sr = tid >> 2;             // staging row (A: 64 rows; B: +64*it)
  const int sc = (tid & 3) * 8;        // staging col chunks: sc, sc+32
  const int e0 = (kg * 8) ^ ((ln & 7) * 8);   // read-side swizzle (champion)

#pragma unroll 1
  for (int hc = 0; hc < 13; ++hc) {
    const int h0 = hc * 64;
    __syncthreads();
    {
      const int rs = (sr & 7) * 8;
      *(h8v*)&Ah[sr * 64 + (sc ^ rs)] =
          *(const h8v*)&yh[(n0 + sr) * 832 + h0 + sc];
      *(h8v*)&Ah[sr * 64 + ((sc + 32) ^ rs)] =
          *(const h8v*)&yh[(n0 + sr) * 832 + h0 + sc + 32];
    }
#pragma unroll
    for (int it = 0; it < 2; ++it) {
      const int r = sr + 64 * it;
      const int rs = (r & 7) * 8;
      *(h8v*)&Bh[r * 64 + (sc ^ rs)] =
          *(const h8v*)&w1h[(i0 + r) * 832 + h0 + sc];
      *(h8v*)&Bh[r * 64 + ((sc + 32) ^ rs)] =
          *(const h8v*)&w1h[(i0 + r) * 832 + h0 + sc + 32];
    }
    __syncthreads();
#pragma unroll
    for (int kk = 0; kk < 4; ++kk) {
      const int cx = (kk * 16) ^ e0;
      h8v a  = *(const h8v*)&Ah[(wn * 32 + ln) * 64 + cx];
      h8v b0 = *(const h8v*)&Bh[(wi * 64 + ln) * 64 + cx];
      h8v b1 = *(const h8v*)&Bh[(wi * 64 + 32 + ln) * 64 + cx];
      acc[0] = __builtin_amdgcn_mfma_f32_32x32x16_f16(a, b0, acc[0], 0, 0, 0);
      acc[1] = __builtin_amdgcn_mfma_f32_32x32x16_f16(a, b1, acc[1], 0, 0, 0);
    }
  }
#pragma unroll
  for (int j = 0; j < 2; ++j) {
    const int i = i0 + wi * 64 + j * 32 + ln;
    if (i < 400) {
      const float bias = b1[i];
#pragma unroll
      for (int reg = 0; reg < 16; ++reg) {
        const int row = n0 + wn * 32 + (reg & 3) + 8 * (reg >> 2) + 4 * kg;
        hout[row * 400 + i] = fmaxf(acc[j][reg] + bias, 0.f);
      }
    }
  }
}

// ---------------- K1 fallback: f32 y input (small-ws path) -------------------
#define E1ST 40
__global__ __launch_bounds__(256, 2)
void k_enc1f(const float* __restrict__ y, const _Float16* __restrict__ w1h,
             const float* __restrict__ b1, float* __restrict__ hout) {
  __shared__ __align__(16) _Float16 Ah[64 * E1ST];
  __shared__ __align__(16) _Float16 Bh[128 * E1ST];
  const int tid = threadIdx.x;
  const int i0 = blockIdx.x * 128;
  const int n0 = blockIdx.y * 64;
  const int wav = tid >> 6, lane = tid & 63;
  const int wn = wav >> 1, wi = wav & 1;
  const int ln = lane & 31, kg = lane >> 5;

  f16v acc[2];
#pragma unroll
  for (int j = 0; j < 2; ++j)
#pragma unroll
    for (int r = 0; r < 16; ++r) acc[j][r] = 0.f;

  const int ar = tid >> 3, ac4 = (tid & 7) * 4;
  const int br = tid >> 2, bg = (tid & 3) * 8;

#pragma unroll 1
  for (int hc = 0; hc < 25; ++hc) {
    const int h0 = hc * 32;
    __syncthreads();
#pragma unroll
    for (int it = 0; it < 2; ++it) {
      int r = ar + 32 * it;
      float4 a = make_float4(0.f, 0.f, 0.f, 0.f);
      if (h0 + ac4 < 784) a = *(const float4*)&y[(n0 + r) * 784 + h0 + ac4];
      h4v hv;
      hv[0] = (_Float16)a.x; hv[1] = (_Float16)a.y;
      hv[2] = (_Float16)a.z; hv[3] = (_Float16)a.w;
      *(h4v*)&Ah[r * E1ST + ac4] = hv;
    }
#pragma unroll
    for (int it = 0; it < 2; ++it) {
      int r = br + 64 * it;
      *(h8v*)&Bh[r * E1ST + bg] = *(const h8v*)&w1h[(i0 + r) * 800 + h0 + bg];
    }
    __syncthreads();
#pragma unroll
    for (int kk = 0; kk < 2; ++kk) {
      const int ko = kk * 16 + kg * 8;
      h8v a  = *(const h8v*)&Ah[(wn * 32 + ln) * E1ST + ko];
      h8v b0 = *(const h8v*)&Bh[(wi * 64 + ln) * E1ST + ko];
      h8v b1 = *(const h8v*)&Bh[(wi * 64 + 32 + ln) * E1ST + ko];
      acc[0] = __builtin_amdgcn_mfma_f32_32x32x16_f16(a, b0, acc[0], 0, 0, 0);
      acc[1] = __builtin_amdgcn_mfma_f32_32x32x16_f16(a, b1, acc[1], 0, 0, 0);
    }
  }
#pragma unroll
  for (int j = 0; j < 2; ++j) {
    const int i = i0 + wi * 64 + j * 32 + ln;
    if (i < 400) {
      const float bias = b1[i];
#pragma unroll
      for (int reg = 0; reg < 16; ++reg) {
        const int row = n0 + wn * 32 + (reg & 3) + 8 * (reg >> 2) + 4 * kg;
        hout[row * 400 + i] = fmaxf(acc[j][reg] + bias, 0.f);
      }
    }
  }
}

// ---------------- k_ezbh: FUSED enc2z + basehk (big-ws path) -----------------
// 256 blocks x 16 rows. ml=h@W2^T+b2 -> z (LDS only) -> base=z@Wz^T+dfb ->
// hkh = relu(base + wx_k) fp16. LDS 141KB (1 blk/CU - was already 1/CU).
__global__ __launch_bounds__(256)
void k_ezbh(const float* __restrict__ h, const float* __restrict__ w2,
            const float* __restrict__ b2, const float* __restrict__ eps,
            const float* __restrict__ dfw, const float* __restrict__ dfb,
            _Float16* __restrict__ hkh) {
  __shared__ __align__(16) float h_lds[16 * 400];    // 25.6KB
  __shared__ __align__(16) float w2_lds[32 * 404];   // 51.7KB
  __shared__ float ml_lds[16 * 32];
  __shared__ __align__(16) float z_l[16 * 16];
  __shared__ __align__(16) float wz[8000];           // 32KB: Wz rows / wxT[16][448]
  __shared__ __align__(16) float base[16 * 448];     // 28.7KB
  const int tid = threadIdx.x;
  const int n0 = blockIdx.x * 16;

  for (int idx = tid; idx < 1600; idx += 256) {
    int r = idx / 100, c = idx - r * 100;
    *(float4*)&h_lds[r * 400 + c * 4] = *(const float4*)&h[(n0 + r) * 400 + c * 4];
  }
  for (int idx = tid; idx < 3200; idx += 256) {
    int r = idx / 100, c = idx - r * 100;
    *(float4*)&w2_lds[r * 404 + c * 4] = *(const float4*)&w2[r * 400 + c * 4];
  }
  for (int idx = tid; idx < 1600; idx += 256) {
    int i = idx >> 2, c = (idx & 3) * 4;
    *(float4*)&wz[i * 20 + c] = *(const float4*)&dfw[i * 32 + c];
  }
  __syncthreads();
  // ml: 256 thr = 32 cols x 8 groups x 2 rows
  {
    const int c_ = tid & 31, rg = tid >> 5;
    float a0 = 0.f, a1 = 0.f;
    for (int q = 0; q < 100; ++q) {
      float4 wv = *(const float4*)&w2_lds[c_ * 404 + q * 4];
      float4 h0 = *(const float4*)&h_lds[(rg * 2 + 0) * 400 + q * 4];
      float4 h1 = *(const float4*)&h_lds[(rg * 2 + 1) * 400 + q * 4];
      a0 += h0.x * wv.x + h0.y * wv.y + h0.z * wv.z + h0.w * wv.w;
      a1 += h1.x * wv.x + h1.y * wv.y + h1.z * wv.z + h1.w * wv.w;
    }
    const float bb = b2[c_];
    ml_lds[(rg * 2 + 0) * 32 + c_] = a0 + bb;
    ml_lds[(rg * 2 + 1) * 32 + c_] = a1 + bb;
  }
  __syncthreads();
  // z in LDS (no global round-trip)
  {
    const int n2 = tid >> 4, l = tid & 15;
    float mu = ml_lds[n2 * 32 + l];
    float lv = ml_lds[n2 * 32 + 16 + l];
    z_l[n2 * 16 + l] = mu + eps[(n0 + n2) * 16 + l] * expf(0.5f * lv);
  }
  __syncthreads();
  // base = z @ Wz^T + dfb
  for (int idx = tid; idx < 7168; idx += 256) {
    int n = idx / 448, i = idx - n * 448;
    float acc = 0.f;
    if (i < 400) {
      acc = dfb[i];
#pragma unroll
      for (int q = 0; q < 4; ++q) {
        float4 zv = *(const float4*)&z_l[n * 16 + q * 4];
        float4 wv = *(const float4*)&wz[i * 20 + q * 4];
        acc += zv.x * wv.x + zv.y * wv.y + zv.z * wv.z + zv.w * wv.w;
      }
    }
    base[n * 448 + i] = acc;
  }
  __syncthreads();
  // overwrite wz with wxT[k][h]
  for (int idx = tid; idx < 7168; idx += 256) {
    int k = idx / 448, hh = idx - k * 448;
    wz[idx] = (hh < 400) ? dfw[hh * 32 + 16 + k] : 0.f;
  }
  __syncthreads();
  // emit hkh: 16k x 16n x 56 chunks of 8 halves
  for (int s = tid; s < 14336; s += 256) {
    int k = s / 896, r2 = s - k * 896;
    int r = r2 / 56, c8 = r2 - r * 56;
    const float* bp = &base[r * 448 + c8 * 8];
    const float* wp = &wz[k * 448 + c8 * 8];
    float4 b0 = *(const float4*)bp, b1 = *(const float4*)(bp + 4);
    float4 w0 = *(const float4*)wp, w1 = *(const float4*)(wp + 4);
    h8v o;
    o[0] = (_Float16)fmaxf(b0.x + w0.x, 0.f);
    o[1] = (_Float16)fmaxf(b0.y + w0.y, 0.f);
    o[2] = (_Float16)fmaxf(b0.z + w0.z, 0.f);
    o[3] = (_Float16)fmaxf(b0.w + w0.w, 0.f);
    o[4] = (_Float16)fmaxf(b1.x + w1.x, 0.f);
    o[5] = (_Float16)fmaxf(b1.y + w1.y, 0.f);
    o[6] = (_Float16)fmaxf(b1.z + w1.z, 0.f);
    o[7] = (_Float16)fmaxf(b1.w + w1.w, 0.f);
    *(h8v*)&hkh[((size_t)k * 4096 + n0 + r) * 448 + c8 * 8] = o;
  }
}

// ---------------- K2 (fallback path): enc2z ----------------
__global__ __launch_bounds__(128, 2)
void k_enc2z(const float* __restrict__ h, const float* __restrict__ w2,
             const float* __restrict__ b2, const float* __restrict__ eps,
             float* __restrict__ z) {
  __shared__ __align__(16) float h_lds[16 * 400];
  __shared__ __align__(16) float w2_lds[32 * 404];
  __shared__ float ml_lds[16 * 32];
  const int tid = threadIdx.x;
  const int n0 = blockIdx.x * 16;
  for (int idx = tid; idx < 1600; idx += 128) {
    int r = idx / 100, c = idx - r * 100;
    *(float4*)&h_lds[r * 400 + c * 4] = *(const float4*)&h[(n0 + r) * 400 + c * 4];
  }
  for (int idx = tid; idx < 3200; idx += 128) {
    int r = idx / 100, c = idx - r * 100;
    *(float4*)&w2_lds[r * 404 + c * 4] = *(const float4*)&w2[r * 400 + c * 4];
  }
  __syncthreads();
  const int c_ = tid & 31, n4 = tid >> 5;
  float a0 = 0.f, a1 = 0.f, a2 = 0.f, a3 = 0.f;
  for (int q = 0; q < 100; ++q) {
    float4 wv = *(const float4*)&w2_lds[c_ * 404 + q * 4];
    float4 h0 = *(const float4*)&h_lds[(n4 * 4 + 0) * 400 + q * 4];
    float4 h1 = *(const float4*)&h_lds[(n4 * 4 + 1) * 400 + q * 4];
    float4 h2 = *(const float4*)&h_lds[(n4 * 4 + 2) * 400 + q * 4];
    float4 h3 = *(const float4*)&h_lds[(n4 * 4 + 3) * 400 + q * 4];
    a0 += h0.x * wv.x + h0.y * wv.y + h0.z * wv.z + h0.w * wv.w;
    a1 += h1.x * wv.x + h1.y * wv.y + h1.z * wv.z + h1.w * wv.w;
    a2 += h2.x * wv.x + h2.y * wv.y + h2.z * wv.z + h2.w * wv.w;
    a3 += h3.x * wv.x + h3.y * wv.y + h3.z * wv.z + h3.w * wv.w;
  }
  const float bb = b2[c_];
  ml_lds[(n4 * 4 + 0) * 32 + c_] = a0 + bb;
  ml_lds[(n4 * 4 + 1) * 32 + c_] = a1 + bb;
  ml_lds[(n4 * 4 + 2) * 32 + c_] = a2 + bb;
  ml_lds[(n4 * 4 + 3) * 32 + c_] = a3 + bb;
  __syncthreads();
  for (int t = tid; t < 256; t += 128) {
    int n2 = t >> 4, l = t & 15;
    float mu = ml_lds[n2 * 32 + l];
    float lv = ml_lds[n2 * 32 + 16 + l];
    z[(n0 + n2) * 16 + l] = mu + eps[(n0 + n2) * 16 + l] * expf(0.5f * lv);
  }
}

// ---------------- K3 (fallback path): base_p = z @ Wz^T + dec_fc_b -----------
__global__ __launch_bounds__(256, 4)
void k_base(const float* __restrict__ z, const float* __restrict__ dfw,
            const float* __restrict__ dfb, float* __restrict__ basep) {
  __shared__ float z_lds[16 * 16];
  __shared__ __align__(16) float wz_lds[400 * 20];
  const int tid = threadIdx.x;
  const int n0 = blockIdx.x * 16;
  if (tid < 64) {
    int n = tid >> 2, c = (tid & 3) * 4;
    *(float4*)&z_lds[n * 16 + c] = *(const float4*)&z[(n0 + n) * 16 + c];
  }
  for (int idx = tid; idx < 1600; idx += 256) {
    int i = idx >> 2, c = (idx & 3) * 4;
    *(float4*)&wz_lds[i * 20 + c] = *(const float4*)&dfw[i * 32 + c];
  }
  __syncthreads();
  for (int idx = tid; idx < 7168; idx += 256) {
    int n = idx / 448, i = idx - n * 448;
    float acc = 0.f;
    if (i < 400) {
      acc = dfb[i];
#pragma unroll
      for (int q = 0; q < 4; ++q) {
        float4 zv = *(const float4*)&z_lds[n * 16 + q * 4];
        float4 wv = *(const float4*)&wz_lds[i * 20 + q * 4];
        acc += zv.x * wv.x + zv.y * wv.y + zv.z * wv.z + zv.w * wv.w;
      }
    }
    basep[(n0 + n) * 448 + i] = acc;
  }
}

// ---------------- K4: R4 champion k_dec2 (145us, UNCHANGED) ----------------
__global__ __launch_bounds__(256, 2)
void k_dec2(const _Float16* __restrict__ hkh, const _Float16* __restrict__ dwh,
            const float* __restrict__ decb, const float* __restrict__ y,
            float* __restrict__ lb) {
  __shared__ __align__(16) _Float16 Ah[128 * 64];
  __shared__ __align__(16) _Float16 Bh[128 * 64];
  __shared__ float red[256];

  const int tid = threadIdx.x;
  const int id  = blockIdx.x;
  const int lin = (id & 7) * 448 + (id >> 3);   // 3584 = 8 XCD x 448, bijective
  const int n_i = lin / 112;
  const int rem = lin - n_i * 112;
  const int k   = rem / 7;
  const int ot  = rem - k * 7;
  const int n0  = n_i * 128;
  const int o0  = ot * 128;

  const int wav = tid >> 6, lane = tid & 63;
  const int wn = wav >> 1, wo = wav & 1;
  const int ln = lane & 31, kg = lane >> 5;

  const int l8 = lane >> 3, l7 = lane & 7;
  const int swh = (l7 * 8) ^ (l8 * 8);
  const _Float16* hkk = hkh + (size_t)k * (4096 * 448);
  const _Float16* pA[4];
  const _Float16* pB[4];
#pragma unroll
  for (int i = 0; i < 4; ++i) {
    const int row = wav * 32 + i * 8 + l8;
    pA[i] = hkk + (size_t)(n0 + row) * 448 + swh;
    pB[i] = dwh + (size_t)(o0 + row) * 448 + swh;
  }

  f16v acc[2][2];
#pragma unroll
  for (int i = 0; i < 2; ++i)
#pragma unroll
    for (int j = 0; j < 2; ++j)
#pragma unroll
      for (int r = 0; r < 16; ++r) acc[i][j][r] = 0.f;

  const int sx = (ln & 7) * 8;          // read-side swizzle
  const int e0 = (kg * 8) ^ sx;
  const int arow = (wn * 64 + ln) * 64;
  const int brow = (wo * 64 + ln) * 64;

#pragma unroll 1
  for (int hc = 0; hc < 7; ++hc) {
    __syncthreads();                    // previous phase done reading LDS
#pragma unroll
    for (int i = 0; i < 4; ++i) {
      gll16(pA[i], &Ah[(wav * 4 + i) * 512]);
      gll16(pB[i], &Bh[(wav * 4 + i) * 512]);
      pA[i] += 64; pB[i] += 64;
    }
    __syncthreads();                    // drains vmcnt -> LDS tiles ready
#pragma unroll
    for (int kk = 0; kk < 4; ++kk) {
      const int cx = (kk * 16) ^ e0;    // slot = logical col ^ swizzle
      h8v a0 = *(const h8v*)&Ah[arow + cx];
      h8v a1 = *(const h8v*)&Ah[arow + 2048 + cx];
      h8v b0 = *(const h8v*)&Bh[brow + cx];
      h8v b1 = *(const h8v*)&Bh[brow + 2048 + cx];
      acc[0][0] = __builtin_amdgcn_mfma_f32_32x32x16_f16(a0, b0, acc[0][0], 0, 0, 0);
      acc[1][0] = __builtin_amdgcn_mfma_f32_32x32x16_f16(a1, b0, acc[1][0], 0, 0, 0);
      acc[0][1] = __builtin_amdgcn_mfma_f32_32x32x16_f16(a0, b1, acc[0][1], 0, 0, 0);
      acc[1][1] = __builtin_amdgcn_mfma_f32_32x32x16_f16(a1, b1, acc[1][1], 0, 0, 0);
    }
  }
  // epilogue: fused BCE. clip-at-100 provably dead (|x|<=~10).
  const int obase = o0 + wo * 64;
  const float bj0 = (obase + ln < 784) ? decb[obase + ln] : 0.f;
  const float bj1 = (obase + 32 + ln < 784) ? decb[obase + 32 + ln] : 0.f;
#pragma unroll
  for (int i = 0; i < 2; ++i) {
#pragma unroll
    for (int reg = 0; reg < 16; ++reg) {
      const int row = wn * 64 + i * 32 + (reg & 3) + 8 * (reg >> 2) + 4 * kg;
      float v = 0.f;
#pragma unroll
      for (int j = 0; j < 2; ++j) {
        const int o = obase + j * 32 + ln;
        if (o < 784) {
          float x = acc[i][j][reg] + (j ? bj1 : bj0);
          float yv = y[(n0 + row) * 784 + o];
          float spx = fmaxf(x, 0.f) + __logf(1.f + __expf(-fabsf(x)));
          v += spx - yv * x;
        }
      }
      v += __shfl_xor(v, 1, 64);
      v += __shfl_xor(v, 2, 64);
      v += __shfl_xor(v, 4, 64);
      v += __shfl_xor(v, 8, 64);
      v += __shfl_xor(v, 16, 64);
      if (ln == 0) red[wo * 128 + row] = v;
    }
  }
  __syncthreads();
  if (tid < 128) {
    float s = red[tid] + red[128 + tid];
    atomicAdd(&lb[(n0 + tid) * 16 + k], s);
  }
}

// ---------------- K4 v1 (fallback if ws too small for hkh) -------------------
#define DST 72
__global__ __launch_bounds__(256, 2)
void k_dec1(const float* __restrict__ basep, const float* __restrict__ dfw,
            const _Float16* __restrict__ dwh, const float* __restrict__ decb,
            const float* __restrict__ y, float* __restrict__ lb) {
  __shared__ __align__(16) _Float16 Ah[128 * DST];
  __shared__ __align__(16) _Float16 Bh[128 * DST];
  __shared__ float wx[448];
  __shared__ float red[256];

  const int tid = threadIdx.x;
  const int id  = blockIdx.x;
  const int lin = (id & 7) * 448 + (id >> 3);
  const int n_i = lin / 112;
  const int rem = lin - n_i * 112;
  const int k   = rem / 7;
  const int ot  = rem - k * 7;
  const int n0  = n_i * 128;
  const int o0  = ot * 128;
  const bool full = (ot < 6);

  const int wav = tid >> 6, lane = tid & 63;
  const int wn = wav >> 1, wo = wav & 1;
  const int ln = lane & 31, kg = lane >> 5;

  for (int i = tid; i < 448; i += 256) wx[i] = (i < 400) ? dfw[i * 32 + 16 + k] : 0.f;

  const int ar = tid >> 4, ac4 = (tid & 15) * 4;
  const int br = tid >> 3, bg = (tid & 7) * 8;
  const float* aptr = basep + (long)(n0 + ar) * 448 + ac4;

  float4 apf[8];
#pragma unroll
  for (int it = 0; it < 8; ++it) apf[it] = *(const float4*)&aptr[(16 * it) * 448];

  f16v acc[2][2];
#pragma unroll
  for (int i = 0; i < 2; ++i)
#pragma unroll
    for (int j = 0; j < 2; ++j)
#pragma unroll
      for (int r = 0; r < 16; ++r) acc[i][j][r] = 0.f;

#pragma unroll 1
  for (int hc = 0; hc < 7; ++hc) {
    const int h0 = hc * 64;
    h8v bpf[4];
#pragma unroll
    for (int it = 0; it < 4; ++it)
      bpf[it] = *(const h8v*)&dwh[(o0 + br + 32 * it) * 448 + h0 + bg];
    __syncthreads();
    {
      float4 w = *(const float4*)&wx[h0 + ac4];
#pragma unroll
      for (int it = 0; it < 8; ++it) {
        int r = ar + 16 * it;
        h4v hv;
        hv[0] = (_Float16)fmaxf(apf[it].x + w.x, 0.f);
        hv[1] = (_Float16)fmaxf(apf[it].y + w.y, 0.f);
        hv[2] = (_Float16)fmaxf(apf[it].z + w.z, 0.f);
        hv[3] = (_Float16)fmaxf(apf[it].w + w.w, 0.f);
        *(h4v*)&Ah[r * DST + ac4] = hv;
      }
    }
#pragma unroll
    for (int it = 0; it < 4; ++it)
      *(h8v*)&Bh[(br + 32 * it) * DST + bg] = bpf[it];
    __syncthreads();
    if (hc < 6) {
      const int hn = (hc + 1) * 64;
#pragma unroll
      for (int it = 0; it < 8; ++it)
        apf[it] = *(const float4*)&aptr[(16 * it) * 448 + hn];
    }
#pragma unroll
    for (int kk = 0; kk < 4; ++kk) {
      const int ko = kk * 16 + kg * 8;
      h8v a0 = *(const h8v*)&Ah[(wn * 64 + ln) * DST + ko];
      h8v a1 = *(const h8v*)&Ah[(wn * 64 + 32 + ln) * DST + ko];
      h8v b0 = *(const h8v*)&Bh[(wo * 64 + ln) * DST + ko];
      h8v b1 = *(const h8v*)&Bh[(wo * 64 + 32 + ln) * DST + ko];
      if (full) {
        acc[0][0] = __builtin_amdgcn_mfma_f32_32x32x16_f16(a0, b0, acc[0][0], 0, 0, 0);
        acc[1][0] = __builtin_amdgcn_mfma_f32_32x32x16_f16(a1, b0, acc[1][0], 0, 0, 0);
        acc[0][1] = __builtin_amdgcn_mfma_f32_32x32x16_f16(a0, b1, acc[0][1], 0, 0, 0);
        acc[1][1] = __builtin_amdgcn_mfma_f32_32x32x16_f16(a1, b1, acc[1][1], 0, 0, 0);
      } else if (wo == 0) {
        acc[0][0] = __builtin_amdgcn_mfma_f32_32x32x16_f16(a0, b0, acc[0][0], 0, 0, 0);
        acc[1][0] = __builtin_amdgcn_mfma_f32_32x32x16_f16(a1, b0, acc[1][0], 0, 0, 0);
      }
    }
  }
  const int obase = o0 + wo * 64;
  const float bj0 = (obase + ln < 784) ? decb[obase + ln] : 0.f;
  const float bj1 = (obase + 32 + ln < 784) ? decb[obase + 32 + ln] : 0.f;
#pragma unroll
  for (int i = 0; i < 2; ++i) {
#pragma unroll
    for (int reg = 0; reg < 16; ++reg) {
      const int row = wn * 64 + i * 32 + (reg & 3) + 8 * (reg >> 2) + 4 * kg;
      float v = 0.f;
#pragma unroll
      for (int j = 0; j < 2; ++j) {
        const int o = obase + j * 32 + ln;
        if (o < 784) {
          float x = acc[i][j][reg] + (j ? bj1 : bj0);
          float yv = y[(n0 + row) * 784 + o];
          float spx = fmaxf(x, 0.f) + __logf(1.f + __expf(-fabsf(x)));
          float t2 = fminf(spx, 100.f);
          float t1 = fminf(spx - x, 100.f);
          v += t2 + yv * (t1 - t2);
        }
      }
      v += __shfl_xor(v, 1, 64);
      v += __shfl_xor(v, 2, 64);
      v += __shfl_xor(v, 4, 64);
      v += __shfl_xor(v, 8, 64);
      v += __shfl_xor(v, 16, 64);
      if (ln == 0) red[wo * 128 + row] = v;
    }
  }
  __syncthreads();
  if (tid < 128) {
    float s = red[tid] + red[128 + tid];
    atomicAdd(&lb[(n0 + tid) * 16 + k], s);
  }
}

// ---------------- K5: HMM fwd/bwd + gamma + xi (fused) ----------------
__global__ __launch_bounds__(256, 2)
void k_hmm(const float* __restrict__ lb, const float* __restrict__ lpi,
           const float* __restrict__ lA, float* __restrict__ out) {
  __shared__ float btl[128 * 16];
  __shared__ float ah[128 * 16];
  __shared__ float bh[128 * 16];
  __shared__ float braw[128 * 16];
  __shared__ float A_l[16 * 17];
  __shared__ float pi_l[16];
  __shared__ float sinv_l[128];
  const int tid = threadIdx.x;
  const int b = blockIdx.x;

  for (int idx = tid; idx < 512; idx += 256) {
    float4 v = *(const float4*)&lb[b * 2048 + idx * 4];
    v.x *= -0.01f; v.y *= -0.01f; v.z *= -0.01f; v.w *= -0.01f;
    *(float4*)&btl[idx * 4] = v;
  }
  if (tid < 16) {
    const int j = tid;
    float m = -1e30f;
#pragma unroll
    for (int q = 0; q < 16; ++q) m = fmaxf(m, lA[j * 16 + q]);
    float e[16]; float s = 0.f;
#pragma unroll
    for (int q = 0; q < 16; ++q) { e[q] = expf(lA[j * 16 + q] - m); s += e[q]; }
    float inv = 1.f / s;
#pragma unroll
    for (int q = 0; q < 16; ++q) A_l[j * 17 + q] = e[q] * inv + 1e-9f;
  } else if (tid == 16) {
    float m = -1e30f;
#pragma unroll
    for (int q = 0; q < 16; ++q) m = fmaxf(m, lpi[q]);
    float e[16]; float s = 0.f;
#pragma unroll
    for (int q = 0; q < 16; ++q) { e[q] = expf(lpi[q] - m); s += e[q]; }
    float inv = 1.f / s;
#pragma unroll
    for (int q = 0; q < 16; ++q) pi_l[q] = e[q] * inv + 1e-9f;
  }
  __syncthreads();
  if (tid < 128) {
    const int t = tid;
    float v[16]; float m = -1e30f;
#pragma unroll
    for (int q = 0; q < 16; ++q) { v[q] = btl[t * 16 + q]; m = fmaxf(m, v[q]); }
#pragma unroll
    for (int q = 0; q < 16; ++q) btl[t * 16 + q] = expf(v[q] - m);
  }
  __syncthreads();
  const int lane = tid & 63;
  const int kk = lane & 15, grp = lane >> 4;
  if (tid < 64) {
    float v0 = pi_l[kk] * btl[kk];
    float ss0 = v0;
    ss0 += __shfl_xor(ss0, 1, 64); ss0 += __shfl_xor(ss0, 2, 64);
    ss0 += __shfl_xor(ss0, 4, 64); ss0 += __shfl_xor(ss0, 8, 64);
    if (grp == 0) ah[kk] = v0 / ss0;
    for (int t = 1; t < 128; ++t) {
      float acc = 0.f;
#pragma unroll
      for (int jj = 0; jj < 4; ++jj) {
        int j = grp * 4 + jj;
        acc = fmaf(ah[(t - 1) * 16 + j], A_l[j * 17 + kk], acc);
      }
      acc += __shfl_xor(acc, 16, 64);
      acc += __shfl_xor(acc, 32, 64);
      float v = acc * btl[t * 16 + kk];
      float ss = v;
      ss += __shfl_xor(ss, 1, 64); ss += __shfl_xor(ss, 2, 64);
      ss += __shfl_xor(ss, 4, 64); ss += __shfl_xor(ss, 8, 64);
      if (grp == 0) ah[t * 16 + kk] = v / ss;
    }
  } else if (tid < 128) {
    if (grp == 0) bh[127 * 16 + kk] = 1.f;
    for (int t = 126; t >= 0; --t) {
      float acc = 0.f;
#pragma unroll
      for (int q = 0; q < 4; ++q) {
        int k2 = grp * 4 + q;
        acc = fmaf(A_l[kk * 17 + k2], btl[(t + 1) * 16 + k2] * bh[(t + 1) * 16 + k2], acc);
      }
      acc += __shfl_xor(acc, 16, 64);
      acc += __shfl_xor(acc, 32, 64);
      float ss = acc;
      ss += __shfl_xor(ss, 1, 64); ss += __shfl_xor(ss, 2, 64);
      ss += __shfl_xor(ss, 4, 64); ss += __shfl_xor(ss, 8, 64);
      if (grp == 0) { braw[t * 16 + kk] = acc; bh[t * 16 + kk] = acc / ss; }
    }
  }
  __syncthreads();
  if (tid < 128) {
    const int t = tid;
    float g[16]; float s2 = 0.f;
#pragma unroll
    for (int q = 0; q < 16; ++q) { g[q] = ah[t * 16 + q] * bh[t * 16 + q]; s2 += g[q]; }
    float inv = 1.f / s2;
#pragma unroll
    for (int c = 0; c < 4; ++c) {
      float4 o;
      o.x = g[c * 4 + 0] * inv; o.y = g[c * 4 + 1] * inv;
      o.z = g[c * 4 + 2] * inv; o.w = g[c * 4 + 3] * inv;
      *(float4*)&out[(b * 128 + t) * 16 + c * 4] = o;
    }
  } else {
    const int t = tid - 128;
    if (t < 127) {
      float s2 = 0.f;
#pragma unroll
      for (int q = 0; q < 16; ++q) s2 += ah[t * 16 + q] * braw[t * 16 + q];
      sinv_l[t] = 1.f / s2;
    }
  }
  __syncthreads();
  const int j = tid >> 4, k2 = tid & 15;
  const float aj = A_l[j * 17 + k2];
  float* xo = out + 65536 + (size_t)b * 127 * 256 + tid;
  for (int t = 0; t < 127; ++t) {
    float val = ah[t * 16 + j] * aj * btl[(t + 1) * 16 + k2] *
                bh[(t + 1) * 16 + k2] * sinv_l[t];
    xo[t * 256] = val;
  }
}

extern "C" void kernel_launch(void* const* d_in, const int* in_sizes, int n_in,
                              void* d_out, int out_size, void* d_ws, size_t ws_size,
                              hipStream_t stream) {
  (void)in_sizes; (void)n_in; (void)out_size;
  const float* y   = (const float*)d_in[0];
  const float* ew1 = (const float*)d_in[1];
  const float* eb1 = (const float*)d_in[2];
  const float* ew2 = (const float*)d_in[3];
  const float* eb2 = (const float*)d_in[4];
  const float* dfw = (const float*)d_in[5];
  const float* dfb = (const float*)d_in[6];
  const float* dw  = (const float*)d_in[7];
  const float* db  = (const float*)d_in[8];
  const float* lpi = (const float*)d_in[9];
  const float* lA  = (const float*)d_in[10];
  const float* eps = (const float*)d_in[11];
  float* out = (float*)d_out;

  float* ws = (float*)d_ws;
  float* h      = ws;                 // then reused as basep (fallback path)
  float* basep  = ws;
  float* z      = ws + 1835008;
  float* lb     = z + 65536;
  _Float16* dwh = (_Float16*)(lb + 65536);    // 896*448 halves
  _Float16* w1h = dwh + 896 * 448;            // 512*832 halves (big) / 512*800 (fallback)
  float* gpad   = (float*)(w1h + 512 * 832);  // spacer
  _Float16* hkh = (_Float16*)(gpad + 65536 * 2 + 4096 + 256);  // 58.7 MB
  // yh aliases hkh: written by k_prep, last read by k_enc1, BEFORE k_ezbh
  // writes hkh (same stream -> ordered). 6.8MB << 58.7MB region.
  _Float16* yh  = hkh;

  const bool big_ws = (ws_size >= 68814848ull);

  if (big_ws) {
    k_prep<<<16544, 256, 0, stream>>>(dw, ew1, y, dwh, w1h, yh, lb);
    k_enc1<<<dim3(4, 64), 256, 0, stream>>>(yh, w1h, eb1, h);
    k_ezbh<<<256, 256, 0, stream>>>(h, ew2, eb2, eps, dfw, dfb, hkh);
    k_dec2<<<3584, 256, 0, stream>>>(hkh, dwh, db, y, lb);
  } else {
    // fallback: w1h at 800-stride layout
    k_prep<<<3168, 256, 0, stream>>>(dw, ew1, y, dwh, w1h, yh, lb);   // yh branch unreached
    k_enc1f<<<dim3(4, 64), 256, 0, stream>>>(y, w1h, eb1, h);
    k_enc2z<<<256, 128, 0, stream>>>(h, ew2, eb2, eps, z);
    k_base<<<256, 256, 0, stream>>>(z, dfw, dfb, basep);
    k_dec1<<<3584, 256, 0, stream>>>(basep, dfw, dwh, db, y, lb);
  }
  k_hmm<<<32, 256, 0, stream>>>(lb, lpi, lA, out);
}